// Round 1
// baseline (926.227 us; speedup 1.0000x reference)
//
#include <hip/hip_runtime.h>
#include <math.h>

#define NN 50000
#define EE 800000
#define FIN 128
#define HID 64
#define CL 40

__device__ __forceinline__ float wave_sum(float v) {
#pragma unroll
  for (int off = 32; off > 0; off >>= 1) v += __shfl_xor(v, off, 64);
  return v;
}
__device__ __forceinline__ float wave_max(float v) {
#pragma unroll
  for (int off = 32; off > 0; off >>= 1) v = fmaxf(v, __shfl_xor(v, off, 64));
  return v;
}
__device__ __forceinline__ float gelu_exact(float x) {
  return 0.5f * x * (1.0f + erff(x * 0.70710678118654752f));
}
__device__ __forceinline__ float leaky02(float x) {
  return x >= 0.f ? x : 0.2f * x;
}

// ---------------- GEMM A: H = x @ [W_gcn | Wl_sage | Wr_sage | W_gat] ----------
// x [N,128], each W [128,64], H [N,256]. blockIdx.y selects the matrix.
__global__ __launch_bounds__(256) void k_gemmA(
    const float* __restrict__ x, const float* __restrict__ W0,
    const float* __restrict__ W1, const float* __restrict__ W2,
    const float* __restrict__ W3, float* __restrict__ H) {
  __shared__ float xst[64][65];  // [k][r] transposed x tile (padded)
  __shared__ float wsm[64][64];  // [k][c]
  const int m = blockIdx.y;
  const float* W = (m == 0) ? W0 : (m == 1) ? W1 : (m == 2) ? W2 : W3;
  const int rbase = blockIdx.x * 64;
  const int t = threadIdx.x;
  const int r0 = (t >> 4) * 4, c0 = (t & 15) * 4;
  float acc[4][4] = {};
  for (int kc = 0; kc < FIN; kc += 64) {
    for (int idx = t; idx < 64 * 64; idx += 256) {
      int k = idx & 63, r = idx >> 6;
      int row = rbase + r;
      xst[k][r] = (row < NN) ? x[(size_t)row * FIN + kc + k] : 0.f;
    }
    for (int idx = t; idx < 64 * 64; idx += 256) {
      int k = idx >> 6, c = idx & 63;
      wsm[k][c] = W[(kc + k) * HID + c];
    }
    __syncthreads();
#pragma unroll 8
    for (int k = 0; k < 64; ++k) {
      float a[4], b[4];
#pragma unroll
      for (int i = 0; i < 4; ++i) a[i] = xst[k][r0 + i];
#pragma unroll
      for (int j = 0; j < 4; ++j) b[j] = wsm[k][c0 + j];
#pragma unroll
      for (int i = 0; i < 4; ++i)
#pragma unroll
        for (int j = 0; j < 4; ++j) acc[i][j] = fmaf(a[i], b[j], acc[i][j]);
    }
    __syncthreads();
  }
#pragma unroll
  for (int i = 0; i < 4; ++i) {
    int row = rbase + r0 + i;
    if (row < NN) {
#pragma unroll
      for (int j = 0; j < 4; ++j)
        H[(size_t)row * 256 + m * 64 + c0 + j] = acc[i][j];
    }
  }
}

// ---------------- attention scalars: a_s = h_gat@att_src, a_d = h_gat@att_dst ---
__global__ __launch_bounds__(256) void k_att(
    const float* __restrict__ H, const float* __restrict__ att_s,
    const float* __restrict__ att_d, float* __restrict__ a_s,
    float* __restrict__ a_d) {
  int wid = (blockIdx.x * blockDim.x + threadIdx.x) >> 6;
  int lane = threadIdx.x & 63;
  if (wid >= NN) return;
  float h = H[(size_t)wid * 256 + 192 + lane];
  float s1 = wave_sum(h * att_s[lane]);
  float s2 = wave_sum(h * att_d[lane]);
  if (lane == 0) { a_s[wid] = s1; a_d[wid] = s2; }
}

// ---------------- degree: cnt[d] += 1 per edge ---------------------------------
__global__ __launch_bounds__(256) void k_deg(const int* __restrict__ dst,
                                             float* __restrict__ cnt) {
  int e = blockIdx.x * blockDim.x + threadIdx.x;
  if (e < EE) atomicAdd(&cnt[dst[e]], 1.0f);
}

// ---------------- edge pass 1: GCN + SAGE + GAT (fused) ------------------------
__global__ __launch_bounds__(256) void k_edge1(
    const int* __restrict__ src, const int* __restrict__ dst,
    const float* __restrict__ H, const float* __restrict__ a_s,
    const float* __restrict__ a_d, const float* __restrict__ cnt,
    float* __restrict__ accg, float* __restrict__ accs,
    float* __restrict__ acca, float* __restrict__ dgat) {
  int wid = (blockIdx.x * blockDim.x + threadIdx.x) >> 6;
  int lane = threadIdx.x & 63;
  if (wid >= EE) return;
  int s = src[wid], d = dst[wid];
  float ds = rsqrtf(cnt[s] + 1.0f), dd = rsqrtf(cnt[d] + 1.0f);
  float norm = ds * dd;
  float ex = __expf(leaky02(a_s[s] + a_d[d]));
  const float* hrow = H + (size_t)s * 256;
  atomicAdd(&accg[(size_t)d * 64 + lane], hrow[lane] * norm);
  atomicAdd(&accs[(size_t)d * 64 + lane], hrow[64 + lane]);
  atomicAdd(&acca[(size_t)d * 64 + lane], hrow[192 + lane] * ex);
  if (lane == 0) atomicAdd(&dgat[d], ex);
}

// ---------------- node pass: ens = Σ w_i * gelu(branch_i) ----------------------
__global__ __launch_bounds__(256) void k_node1(
    const float* __restrict__ H, const float* __restrict__ accg,
    const float* __restrict__ accs, const float* __restrict__ acca,
    const float* __restrict__ dgat, const float* __restrict__ cnt,
    const float* __restrict__ a_s, const float* __restrict__ a_d,
    const float* __restrict__ b_gcn, const float* __restrict__ bl,
    const float* __restrict__ b_gat, const float* __restrict__ w,
    float* __restrict__ ens) {
  int wid = (blockIdx.x * blockDim.x + threadIdx.x) >> 6;
  int lane = threadIdx.x & 63;
  if (wid >= NN) return;
  float c = cnt[wid];
  float di = rsqrtf(c + 1.0f);
  float dinv2 = di * di;
  // GCN (+ self loop)
  float g = accg[(size_t)wid * 64 + lane] + dinv2 * H[(size_t)wid * 256 + lane] +
            b_gcn[lane];
  g = gelu_exact(g);
  // SAGE (mean agg + root)
  float sg = accs[(size_t)wid * 64 + lane] / fmaxf(c, 1.0f) + bl[lane] +
             H[(size_t)wid * 256 + 128 + lane];
  sg = gelu_exact(sg);
  // GAT (+ self loop)
  float exl = __expf(leaky02(a_s[wid] + a_d[wid]));
  float ga = (acca[(size_t)wid * 64 + lane] +
              exl * H[(size_t)wid * 256 + 192 + lane]) /
                 (dgat[wid] + exl + 1e-16f) +
             b_gat[lane];
  ga = gelu_exact(ga);
  ens[(size_t)wid * 64 + lane] = w[0] * g + w[1] * sg + w[2] * ga;
}

// ---------------- GEMM B: QKVS = ens @ [Wq|Wk|Wv|Wskip] + bias -----------------
// ens [N,64], each W [64,40], QKVS [N,160]
__global__ __launch_bounds__(256) void k_gemmB(
    const float* __restrict__ ens, const float* __restrict__ W0,
    const float* __restrict__ W1, const float* __restrict__ W2,
    const float* __restrict__ W3, const float* __restrict__ b0,
    const float* __restrict__ b1, const float* __restrict__ b2,
    const float* __restrict__ b3, float* __restrict__ QKVS) {
  __shared__ float est[64][65];  // [k][r]
  __shared__ float wt[64][40];   // [k][c]
  const int m = blockIdx.y;
  const float* W = (m == 0) ? W0 : (m == 1) ? W1 : (m == 2) ? W2 : W3;
  const float* bias = (m == 0) ? b0 : (m == 1) ? b1 : (m == 2) ? b2 : b3;
  const int rbase = blockIdx.x * 64;
  const int t = threadIdx.x;
  const int r0 = (t >> 3) * 2, c0 = (t & 7) * 5;
  for (int idx = t; idx < 64 * 64; idx += 256) {
    int k = idx & 63, r = idx >> 6;
    int row = rbase + r;
    est[k][r] = (row < NN) ? ens[(size_t)row * HID + k] : 0.f;
  }
  for (int idx = t; idx < 64 * CL; idx += 256) {
    int k = idx / CL, c = idx % CL;
    wt[k][c] = W[k * CL + c];
  }
  __syncthreads();
  float acc[2][5] = {};
#pragma unroll 8
  for (int k = 0; k < 64; ++k) {
    float a[2], b[5];
#pragma unroll
    for (int i = 0; i < 2; ++i) a[i] = est[k][r0 + i];
#pragma unroll
    for (int j = 0; j < 5; ++j) b[j] = wt[k][c0 + j];
#pragma unroll
    for (int i = 0; i < 2; ++i)
#pragma unroll
      for (int j = 0; j < 5; ++j) acc[i][j] = fmaf(a[i], b[j], acc[i][j]);
  }
#pragma unroll
  for (int i = 0; i < 2; ++i) {
    int row = rbase + r0 + i;
    if (row < NN) {
#pragma unroll
      for (int j = 0; j < 5; ++j)
        QKVS[(size_t)row * 160 + m * CL + c0 + j] = acc[i][j] + bias[c0 + j];
    }
  }
}

// ---------------- edge pass 2: transformer attention ---------------------------
__global__ __launch_bounds__(256) void k_edge2(
    const int* __restrict__ src, const int* __restrict__ dst,
    const float* __restrict__ QKVS, float* __restrict__ dtr,
    float* __restrict__ acctr) {
  int wid = (blockIdx.x * blockDim.x + threadIdx.x) >> 6;
  int lane = threadIdx.x & 63;
  if (wid >= EE) return;
  int s = src[wid], d = dst[wid];
  bool valid = lane < CL;
  float p = 0.f;
  if (valid)
    p = QKVS[(size_t)d * 160 + lane] * QKVS[(size_t)s * 160 + 40 + lane];
  float sum = wave_sum(p);
  float ex = __expf(sum * 0.15811388300841897f);  // 1/sqrt(40)
  if (lane == 0) atomicAdd(&dtr[d], ex);
  if (valid)
    atomicAdd(&acctr[(size_t)d * CL + lane],
              ex * QKVS[(size_t)s * 160 + 80 + lane]);
}

// ---------------- final: out = log_softmax(attn + skip) ------------------------
__global__ __launch_bounds__(256) void k_final(
    const float* __restrict__ acctr, const float* __restrict__ dtr,
    const float* __restrict__ QKVS, float* __restrict__ out) {
  int wid = (blockIdx.x * blockDim.x + threadIdx.x) >> 6;
  int lane = threadIdx.x & 63;
  if (wid >= NN) return;
  bool valid = lane < CL;
  float o = valid ? acctr[(size_t)wid * CL + lane] / (dtr[wid] + 1e-16f) +
                        QKVS[(size_t)wid * 160 + 120 + lane]
                  : -3.0e38f;
  float m = wave_max(o);
  float eo = valid ? __expf(o - m) : 0.f;
  float ssum = wave_sum(eo);
  if (valid) out[(size_t)wid * CL + lane] = o - m - logf(ssum);
}

extern "C" void kernel_launch(void* const* d_in, const int* in_sizes, int n_in,
                              void* d_out, int out_size, void* d_ws,
                              size_t ws_size, hipStream_t stream) {
  const float* x     = (const float*)d_in[0];
  const int*   ei    = (const int*)d_in[1];
  const float* w     = (const float*)d_in[2];
  const float* W_gcn = (const float*)d_in[3];
  const float* b_gcn = (const float*)d_in[4];
  const float* Wl    = (const float*)d_in[5];
  const float* bl    = (const float*)d_in[6];
  const float* Wr    = (const float*)d_in[7];
  const float* W_gat = (const float*)d_in[8];
  const float* att_s = (const float*)d_in[9];
  const float* att_d = (const float*)d_in[10];
  const float* b_gat = (const float*)d_in[11];
  const float* Wq    = (const float*)d_in[12];
  const float* bq    = (const float*)d_in[13];
  const float* Wk    = (const float*)d_in[14];
  const float* bk    = (const float*)d_in[15];
  const float* Wv    = (const float*)d_in[16];
  const float* bv    = (const float*)d_in[17];
  const float* Wsk   = (const float*)d_in[18];
  const float* bsk   = (const float*)d_in[19];
  float* out = (float*)d_out;
  float* ws  = (float*)d_ws;

  const int* src = ei;
  const int* dst = ei + EE;

  // workspace layout (floats). QKVS overlays the (dead-after-node1) acc_* region.
  float* H     = ws;                          // 256N
  float* ens   = ws + (size_t)256 * NN;       // 64N
  float* a_s   = ws + (size_t)320 * NN;       // N
  float* a_d   = ws + (size_t)321 * NN;       // N
  float* cnt   = ws + (size_t)322 * NN;       // N   -- zero region start
  float* dgat  = ws + (size_t)323 * NN;       // N
  float* dtr   = ws + (size_t)324 * NN;       // N
  float* acctr = ws + (size_t)325 * NN;       // 40N
  float* accg  = ws + (size_t)365 * NN;       // 64N
  float* accs  = ws + (size_t)429 * NN;       // 64N
  float* acca  = ws + (size_t)493 * NN;       // 64N -- zero region end (557N)
  float* qkvs  = ws + (size_t)365 * NN;       // 160N overlay on accg/accs/acca

  // zero all accumulators (every call: ws is not re-poisoned between replays)
  hipMemsetAsync(cnt, 0, (size_t)235 * NN * sizeof(float), stream);

  dim3 gA((NN + 63) / 64, 4);
  k_gemmA<<<gA, 256, 0, stream>>>(x, W_gcn, Wl, Wr, W_gat, H);
  k_att<<<(NN + 3) / 4, 256, 0, stream>>>(H, att_s, att_d, a_s, a_d);
  k_deg<<<(EE + 255) / 256, 256, 0, stream>>>(dst, cnt);
  k_edge1<<<(EE + 3) / 4, 256, 0, stream>>>(src, dst, H, a_s, a_d, cnt, accg,
                                            accs, acca, dgat);
  k_node1<<<(NN + 3) / 4, 256, 0, stream>>>(H, accg, accs, acca, dgat, cnt, a_s,
                                            a_d, b_gcn, bl, b_gat, w, ens);
  dim3 gB((NN + 63) / 64, 4);
  k_gemmB<<<gB, 256, 0, stream>>>(ens, Wq, Wk, Wv, Wsk, bq, bk, bv, bsk, qkvs);
  k_edge2<<<(EE + 3) / 4, 256, 0, stream>>>(src, dst, qkvs, dtr, acctr);
  k_final<<<(NN + 3) / 4, 256, 0, stream>>>(acctr, dtr, qkvs, out);
}

// Round 2
// 578.868 us; speedup vs baseline: 1.6001x; 1.6001x over previous
//
#include <hip/hip_runtime.h>
#include <math.h>

#define NN 50000
#define EE 800000
#define FIN 128
#define HID 64
#define CL 40

__device__ __forceinline__ float wave_sum(float v) {
#pragma unroll
  for (int off = 32; off > 0; off >>= 1) v += __shfl_xor(v, off, 64);
  return v;
}
__device__ __forceinline__ float wave_max(float v) {
#pragma unroll
  for (int off = 32; off > 0; off >>= 1) v = fmaxf(v, __shfl_xor(v, off, 64));
  return v;
}
__device__ __forceinline__ float gelu_exact(float x) {
  return 0.5f * x * (1.0f + erff(x * 0.70710678118654752f));
}
__device__ __forceinline__ float leaky02(float x) {
  return x >= 0.f ? x : 0.2f * x;
}

// ---------------- GEMM A: H = x @ [W_gcn | Wl_sage | W_gat | Wr_sage] ----------
// Column order chosen so the edge pass gathers H[s][0:192] contiguously.
__global__ __launch_bounds__(256) void k_gemmA(
    const float* __restrict__ x, const float* __restrict__ W0,
    const float* __restrict__ W1, const float* __restrict__ W2,
    const float* __restrict__ W3, float* __restrict__ H) {
  __shared__ float xst[64][65];  // [k][r] transposed x tile (padded)
  __shared__ float wsm[64][64];  // [k][c]
  const int m = blockIdx.y;
  const float* W = (m == 0) ? W0 : (m == 1) ? W1 : (m == 2) ? W2 : W3;
  const int rbase = blockIdx.x * 64;
  const int t = threadIdx.x;
  const int r0 = (t >> 4) * 4, c0 = (t & 15) * 4;
  float acc[4][4] = {};
  for (int kc = 0; kc < FIN; kc += 64) {
    for (int idx = t; idx < 64 * 64; idx += 256) {
      int k = idx & 63, r = idx >> 6;
      int row = rbase + r;
      xst[k][r] = (row < NN) ? x[(size_t)row * FIN + kc + k] : 0.f;
    }
    for (int idx = t; idx < 64 * 64; idx += 256) {
      int k = idx >> 6, c = idx & 63;
      wsm[k][c] = W[(kc + k) * HID + c];
    }
    __syncthreads();
#pragma unroll 8
    for (int k = 0; k < 64; ++k) {
      float a[4], b[4];
#pragma unroll
      for (int i = 0; i < 4; ++i) a[i] = xst[k][r0 + i];
#pragma unroll
      for (int j = 0; j < 4; ++j) b[j] = wsm[k][c0 + j];
#pragma unroll
      for (int i = 0; i < 4; ++i)
#pragma unroll
        for (int j = 0; j < 4; ++j) acc[i][j] = fmaf(a[i], b[j], acc[i][j]);
    }
    __syncthreads();
  }
#pragma unroll
  for (int i = 0; i < 4; ++i) {
    int row = rbase + r0 + i;
    if (row < NN) {
#pragma unroll
      for (int j = 0; j < 4; ++j)
        H[(size_t)row * 256 + m * 64 + c0 + j] = acc[i][j];
    }
  }
}

// ---------------- attention scalars (GAT block = cols 128..191) ----------------
__global__ __launch_bounds__(256) void k_att(
    const float* __restrict__ H, const float* __restrict__ att_s,
    const float* __restrict__ att_d, float* __restrict__ a_s,
    float* __restrict__ a_d) {
  int wid = (blockIdx.x * blockDim.x + threadIdx.x) >> 6;
  int lane = threadIdx.x & 63;
  if (wid >= NN) return;
  float h = H[(size_t)wid * 256 + 128 + lane];
  float s1 = wave_sum(h * att_s[lane]);
  float s2 = wave_sum(h * att_d[lane]);
  if (lane == 0) { a_s[wid] = s1; a_d[wid] = s2; }
}

// ---------------- histogram of dst ---------------------------------------------
__global__ __launch_bounds__(256) void k_hist(const int* __restrict__ dst,
                                              int* __restrict__ cnt) {
  int e = blockIdx.x * blockDim.x + threadIdx.x;
  if (e < EE) atomicAdd(&cnt[dst[e]], 1);
}

// ---------------- exclusive scan (single block) + aux fill ---------------------
__global__ __launch_bounds__(1024) void k_scan(
    const int* __restrict__ cnt, int* __restrict__ offs,
    int* __restrict__ cursor, const float* __restrict__ a_s,
    float2* __restrict__ aux) {
  __shared__ int ts[1024];
  int t = threadIdx.x;
  const int CH = (NN + 1023) / 1024;  // 49
  int lo = t * CH, hi = min(lo + CH, NN);
  int s = 0;
  for (int i = lo; i < hi; ++i) s += cnt[i];
  ts[t] = s;
  __syncthreads();
  for (int off = 1; off < 1024; off <<= 1) {
    int v = (t >= off) ? ts[t - off] : 0;
    __syncthreads();
    ts[t] += v;
    __syncthreads();
  }
  int run = (t == 0) ? 0 : ts[t - 1];
  for (int i = lo; i < hi; ++i) {
    offs[i] = run;
    cursor[i] = run;
    run += cnt[i];
    aux[i] = make_float2(rsqrtf((float)cnt[i] + 1.0f), a_s[i]);
  }
}

// ---------------- counting-sort scatter: srcidx sorted by dst ------------------
__global__ __launch_bounds__(256) void k_scatter(const int* __restrict__ src,
                                                 const int* __restrict__ dst,
                                                 int* __restrict__ cursor,
                                                 int* __restrict__ srcidx) {
  int e = blockIdx.x * blockDim.x + threadIdx.x;
  if (e < EE) {
    int p = atomicAdd(&cursor[dst[e]], 1);
    srcidx[p] = src[e];
  }
}

// ---------------- fused GCN+SAGE+GAT aggregation + gelu ensemble ---------------
__global__ __launch_bounds__(256) void k_agg1(
    const int* __restrict__ srcidx, const int* __restrict__ offs,
    const int* __restrict__ cnt, const float* __restrict__ H,
    const float2* __restrict__ aux, const float* __restrict__ a_d,
    const float* __restrict__ b_gcn, const float* __restrict__ bl,
    const float* __restrict__ b_gat, const float* __restrict__ w,
    float* __restrict__ ens) {
  int node = (blockIdx.x * blockDim.x + threadIdx.x) >> 6;
  int lane = threadIdx.x & 63;
  if (node >= NN) return;
  int beg = offs[node];
  int c = cnt[node];
  int end = beg + c;
  float2 axd = aux[node];  // {dinv_d, a_s_d}
  float dd = axd.x;
  float a_dd = a_d[node];
  float accg = 0.f, accs = 0.f, acca = 0.f, dg = 0.f;
  int p = beg;
  for (; p + 1 < end; p += 2) {
    int s0 = srcidx[p], s1 = srcidx[p + 1];
    float2 ax0 = aux[s0], ax1 = aux[s1];
    const float* h0 = H + (size_t)s0 * 256;
    const float* h1 = H + (size_t)s1 * 256;
    float g0 = h0[lane], g1 = h1[lane];
    float q0 = h0[64 + lane], q1 = h1[64 + lane];
    float t0 = h0[128 + lane], t1 = h1[128 + lane];
    float ex0 = __expf(leaky02(ax0.y + a_dd));
    float ex1 = __expf(leaky02(ax1.y + a_dd));
    accg = fmaf(g0, ax0.x * dd, accg);
    accg = fmaf(g1, ax1.x * dd, accg);
    accs += q0 + q1;
    acca = fmaf(t0, ex0, acca);
    acca = fmaf(t1, ex1, acca);
    dg += ex0 + ex1;
  }
  if (p < end) {
    int s0 = srcidx[p];
    float2 ax0 = aux[s0];
    const float* h0 = H + (size_t)s0 * 256;
    float ex0 = __expf(leaky02(ax0.y + a_dd));
    accg = fmaf(h0[lane], ax0.x * dd, accg);
    accs += h0[64 + lane];
    acca = fmaf(h0[128 + lane], ex0, acca);
    dg += ex0;
  }
  const float* hd = H + (size_t)node * 256;
  float exl = __expf(leaky02(axd.y + a_dd));
  float g = accg + dd * dd * hd[lane] + b_gcn[lane];
  float sg = accs / fmaxf((float)c, 1.0f) + bl[lane] + hd[192 + lane];
  float ga = (acca + exl * hd[128 + lane]) / (dg + exl + 1e-16f) + b_gat[lane];
  ens[(size_t)node * 64 + lane] =
      w[0] * gelu_exact(g) + w[1] * gelu_exact(sg) + w[2] * gelu_exact(ga);
}

// ---------------- GEMM B: QKVS = ens @ [Wq|Wk|Wv|Wskip] + bias -----------------
__global__ __launch_bounds__(256) void k_gemmB(
    const float* __restrict__ ens, const float* __restrict__ W0,
    const float* __restrict__ W1, const float* __restrict__ W2,
    const float* __restrict__ W3, const float* __restrict__ b0,
    const float* __restrict__ b1, const float* __restrict__ b2,
    const float* __restrict__ b3, float* __restrict__ QKVS) {
  __shared__ float est[64][65];  // [k][r]
  __shared__ float wt[64][40];   // [k][c]
  const int m = blockIdx.y;
  const float* W = (m == 0) ? W0 : (m == 1) ? W1 : (m == 2) ? W2 : W3;
  const float* bias = (m == 0) ? b0 : (m == 1) ? b1 : (m == 2) ? b2 : b3;
  const int rbase = blockIdx.x * 64;
  const int t = threadIdx.x;
  const int r0 = (t >> 3) * 2, c0 = (t & 7) * 5;
  for (int idx = t; idx < 64 * 64; idx += 256) {
    int k = idx & 63, r = idx >> 6;
    int row = rbase + r;
    est[k][r] = (row < NN) ? ens[(size_t)row * HID + k] : 0.f;
  }
  for (int idx = t; idx < 64 * CL; idx += 256) {
    int k = idx / CL, c = idx % CL;
    wt[k][c] = W[k * CL + c];
  }
  __syncthreads();
  float acc[2][5] = {};
#pragma unroll 8
  for (int k = 0; k < 64; ++k) {
    float a[2], b[5];
#pragma unroll
    for (int i = 0; i < 2; ++i) a[i] = est[k][r0 + i];
#pragma unroll
    for (int j = 0; j < 5; ++j) b[j] = wt[k][c0 + j];
#pragma unroll
    for (int i = 0; i < 2; ++i)
#pragma unroll
      for (int j = 0; j < 5; ++j) acc[i][j] = fmaf(a[i], b[j], acc[i][j]);
  }
#pragma unroll
  for (int i = 0; i < 2; ++i) {
    int row = rbase + r0 + i;
    if (row < NN) {
#pragma unroll
      for (int j = 0; j < 5; ++j)
        QKVS[(size_t)row * 160 + m * CL + c0 + j] = acc[i][j] + bias[c0 + j];
    }
  }
}

// ---------------- fused transformer aggregation + log_softmax ------------------
__global__ __launch_bounds__(256) void k_agg2(
    const int* __restrict__ srcidx, const int* __restrict__ offs,
    const int* __restrict__ cnt, const float* __restrict__ QKVS,
    float* __restrict__ out) {
  int node = (blockIdx.x * blockDim.x + threadIdx.x) >> 6;
  int lane = threadIdx.x & 63;
  if (node >= NN) return;
  bool valid = lane < CL;
  int beg = offs[node];
  int end = beg + cnt[node];
  const float* rd = QKVS + (size_t)node * 160;
  float q = valid ? rd[lane] : 0.f;
  float skip = valid ? rd[120 + lane] : 0.f;
  float den = 0.f, accv = 0.f;
  const float ISQ = 0.15811388300841897f;  // 1/sqrt(40)
  int p = beg;
  for (; p + 1 < end; p += 2) {
    int s0 = srcidx[p], s1 = srcidx[p + 1];
    const float* r0 = QKVS + (size_t)s0 * 160;
    const float* r1 = QKVS + (size_t)s1 * 160;
    float k0 = valid ? r0[40 + lane] : 0.f, v0 = valid ? r0[80 + lane] : 0.f;
    float k1 = valid ? r1[40 + lane] : 0.f, v1 = valid ? r1[80 + lane] : 0.f;
    float e0 = __expf(wave_sum(q * k0) * ISQ);
    float e1 = __expf(wave_sum(q * k1) * ISQ);
    den += e0 + e1;
    accv = fmaf(e0, v0, accv);
    accv = fmaf(e1, v1, accv);
  }
  if (p < end) {
    int s0 = srcidx[p];
    const float* r0 = QKVS + (size_t)s0 * 160;
    float k0 = valid ? r0[40 + lane] : 0.f, v0 = valid ? r0[80 + lane] : 0.f;
    float e0 = __expf(wave_sum(q * k0) * ISQ);
    den += e0;
    accv = fmaf(e0, v0, accv);
  }
  float o = valid ? accv / (den + 1e-16f) + skip : -3.0e38f;
  float m = wave_max(o);
  float eo = valid ? __expf(o - m) : 0.f;
  float ssum = wave_sum(eo);
  if (valid) out[(size_t)node * CL + lane] = o - m - logf(ssum);
}

extern "C" void kernel_launch(void* const* d_in, const int* in_sizes, int n_in,
                              void* d_out, int out_size, void* d_ws,
                              size_t ws_size, hipStream_t stream) {
  const float* x     = (const float*)d_in[0];
  const int*   ei    = (const int*)d_in[1];
  const float* w     = (const float*)d_in[2];
  const float* W_gcn = (const float*)d_in[3];
  const float* b_gcn = (const float*)d_in[4];
  const float* Wl    = (const float*)d_in[5];
  const float* bl    = (const float*)d_in[6];
  const float* Wr    = (const float*)d_in[7];
  const float* W_gat = (const float*)d_in[8];
  const float* att_s = (const float*)d_in[9];
  const float* att_d = (const float*)d_in[10];
  const float* b_gat = (const float*)d_in[11];
  const float* Wq    = (const float*)d_in[12];
  const float* bq    = (const float*)d_in[13];
  const float* Wk    = (const float*)d_in[14];
  const float* bk    = (const float*)d_in[15];
  const float* Wv    = (const float*)d_in[16];
  const float* bv    = (const float*)d_in[17];
  const float* Wsk   = (const float*)d_in[18];
  const float* bsk   = (const float*)d_in[19];
  float* out = (float*)d_out;
  float* ws  = (float*)d_ws;

  const int* src = ei;
  const int* dst = ei + EE;

  // workspace layout
  float*  H      = ws;                            // 256N floats
  float*  ens    = ws + (size_t)256 * NN;         // 64N
  float*  a_s    = ws + (size_t)320 * NN;         // N
  float*  a_d    = ws + (size_t)321 * NN;         // N
  float2* aux    = (float2*)(ws + (size_t)322 * NN);  // N float2 (2N floats)
  float*  qkvs   = ws + (size_t)324 * NN;         // 160N
  int*    ibase  = (int*)(ws + (size_t)484 * NN);
  int*    cnt    = ibase;                         // N
  int*    offs   = ibase + NN;                    // N
  int*    cursor = ibase + 2 * NN;                // N
  int*    srcidx = ibase + 3 * NN;                // EE

  hipMemsetAsync(cnt, 0, (size_t)NN * sizeof(int), stream);

  dim3 gA((NN + 63) / 64, 4);
  k_gemmA<<<gA, 256, 0, stream>>>(x, W_gcn, Wl, W_gat, Wr, H);
  k_att<<<(NN + 3) / 4, 256, 0, stream>>>(H, att_s, att_d, a_s, a_d);
  k_hist<<<(EE + 255) / 256, 256, 0, stream>>>(dst, cnt);
  k_scan<<<1, 1024, 0, stream>>>(cnt, offs, cursor, a_s, aux);
  k_scatter<<<(EE + 255) / 256, 256, 0, stream>>>(src, dst, cursor, srcidx);
  k_agg1<<<(NN + 3) / 4, 256, 0, stream>>>(srcidx, offs, cnt, H, aux, a_d,
                                           b_gcn, bl, b_gat, w, ens);
  dim3 gB((NN + 63) / 64, 4);
  k_gemmB<<<gB, 256, 0, stream>>>(ens, Wq, Wk, Wv, Wsk, bq, bk, bv, bsk, qkvs);
  k_agg2<<<(NN + 3) / 4, 256, 0, stream>>>(srcidx, offs, cnt, qkvs, out);
}

// Round 3
// 402.406 us; speedup vs baseline: 2.3017x; 1.4385x over previous
//
#include <hip/hip_runtime.h>
#include <math.h>

#define NN 50000
#define EE 800000
#define FIN 128
#define HID 64
#define CL 40
#define SCB 256
#define NBLK ((NN + SCB - 1) / SCB)  // 196

__device__ __forceinline__ float wave_sum(float v) {
#pragma unroll
  for (int off = 32; off > 0; off >>= 1) v += __shfl_xor(v, off, 64);
  return v;
}
__device__ __forceinline__ int wave_sum_i(int v) {
#pragma unroll
  for (int off = 32; off > 0; off >>= 1) v += __shfl_xor(v, off, 64);
  return v;
}
__device__ __forceinline__ float wave_max(float v) {
#pragma unroll
  for (int off = 32; off > 0; off >>= 1) v = fmaxf(v, __shfl_xor(v, off, 64));
  return v;
}
__device__ __forceinline__ float gelu_exact(float x) {
  return 0.5f * x * (1.0f + erff(x * 0.70710678118654752f));
}
__device__ __forceinline__ float leaky02(float x) {
  return x >= 0.f ? x : 0.2f * x;
}

// ---------------- GEMM A: H = x @ [W_gcn | Wl_sage | W_gat | Wr_sage] ----------
// Column order chosen so the edge pass gathers H[s][0:192] contiguously.
__global__ __launch_bounds__(256) void k_gemmA(
    const float* __restrict__ x, const float* __restrict__ W0,
    const float* __restrict__ W1, const float* __restrict__ W2,
    const float* __restrict__ W3, float* __restrict__ H) {
  __shared__ float xst[64][65];  // [k][r] transposed x tile (padded)
  __shared__ float wsm[64][64];  // [k][c]
  const int m = blockIdx.y;
  const float* W = (m == 0) ? W0 : (m == 1) ? W1 : (m == 2) ? W2 : W3;
  const int rbase = blockIdx.x * 64;
  const int t = threadIdx.x;
  const int r0 = (t >> 4) * 4, c0 = (t & 15) * 4;
  float acc[4][4] = {};
  for (int kc = 0; kc < FIN; kc += 64) {
    for (int idx = t; idx < 64 * 64; idx += 256) {
      int k = idx & 63, r = idx >> 6;
      int row = rbase + r;
      xst[k][r] = (row < NN) ? x[(size_t)row * FIN + kc + k] : 0.f;
    }
    for (int idx = t; idx < 64 * 64; idx += 256) {
      int k = idx >> 6, c = idx & 63;
      wsm[k][c] = W[(kc + k) * HID + c];
    }
    __syncthreads();
#pragma unroll 8
    for (int k = 0; k < 64; ++k) {
      float a[4], b[4];
#pragma unroll
      for (int i = 0; i < 4; ++i) a[i] = xst[k][r0 + i];
#pragma unroll
      for (int j = 0; j < 4; ++j) b[j] = wsm[k][c0 + j];
#pragma unroll
      for (int i = 0; i < 4; ++i)
#pragma unroll
        for (int j = 0; j < 4; ++j) acc[i][j] = fmaf(a[i], b[j], acc[i][j]);
    }
    __syncthreads();
  }
#pragma unroll
  for (int i = 0; i < 4; ++i) {
    int row = rbase + r0 + i;
    if (row < NN) {
#pragma unroll
      for (int j = 0; j < 4; ++j)
        H[(size_t)row * 256 + m * 64 + c0 + j] = acc[i][j];
    }
  }
}

// ---------------- attention scalars (GAT block = cols 128..191) ----------------
__global__ __launch_bounds__(256) void k_att(
    const float* __restrict__ H, const float* __restrict__ att_s,
    const float* __restrict__ att_d, float* __restrict__ a_s,
    float* __restrict__ a_d) {
  int wid = (blockIdx.x * blockDim.x + threadIdx.x) >> 6;
  int lane = threadIdx.x & 63;
  if (wid >= NN) return;
  float h = H[(size_t)wid * 256 + 128 + lane];
  float s1 = wave_sum(h * att_s[lane]);
  float s2 = wave_sum(h * att_d[lane]);
  if (lane == 0) { a_s[wid] = s1; a_d[wid] = s2; }
}

// ---------------- histogram of dst ---------------------------------------------
__global__ __launch_bounds__(256) void k_hist(const int* __restrict__ dst,
                                              int* __restrict__ cnt) {
  int e = blockIdx.x * blockDim.x + threadIdx.x;
  if (e < EE) atomicAdd(&cnt[dst[e]], 1);
}

// ---------------- 3-phase parallel exclusive scan ------------------------------
__global__ __launch_bounds__(SCB) void k_bsum(const int* __restrict__ cnt,
                                              int* __restrict__ bsum) {
  __shared__ int wsm[4];
  int i = blockIdx.x * SCB + threadIdx.x;
  int v = (i < NN) ? cnt[i] : 0;
  int s = wave_sum_i(v);
  int lane = threadIdx.x & 63, wv = threadIdx.x >> 6;
  if (lane == 0) wsm[wv] = s;
  __syncthreads();
  if (threadIdx.x == 0) bsum[blockIdx.x] = wsm[0] + wsm[1] + wsm[2] + wsm[3];
}

__global__ __launch_bounds__(SCB) void k_bscan(const int* __restrict__ bsum,
                                               int* __restrict__ boffs) {
  __shared__ int ts[SCB];
  int t = threadIdx.x;
  int v = (t < NBLK) ? bsum[t] : 0;
  ts[t] = v;
  __syncthreads();
  for (int off = 1; off < SCB; off <<= 1) {
    int u = (t >= off) ? ts[t - off] : 0;
    __syncthreads();
    ts[t] += u;
    __syncthreads();
  }
  if (t < NBLK) boffs[t] = ts[t] - v;  // exclusive
}

__global__ __launch_bounds__(SCB) void k_apply(
    const int* __restrict__ cnt, const int* __restrict__ boffs,
    int* __restrict__ offs, int* __restrict__ cursor,
    const float* __restrict__ a_s, float2* __restrict__ aux) {
  __shared__ int ts[SCB];
  int i = blockIdx.x * SCB + threadIdx.x;
  int t = threadIdx.x;
  int v = (i < NN) ? cnt[i] : 0;
  ts[t] = v;
  __syncthreads();
  for (int off = 1; off < SCB; off <<= 1) {
    int u = (t >= off) ? ts[t - off] : 0;
    __syncthreads();
    ts[t] += u;
    __syncthreads();
  }
  if (i < NN) {
    int ex = ts[t] - v + boffs[blockIdx.x];
    offs[i] = ex;
    cursor[i] = ex;
    aux[i] = make_float2(rsqrtf((float)v + 1.0f), a_s[i]);
  }
}

// ---------------- counting-sort scatter: srcidx sorted by dst ------------------
__global__ __launch_bounds__(256) void k_scatter(const int* __restrict__ src,
                                                 const int* __restrict__ dst,
                                                 int* __restrict__ cursor,
                                                 int* __restrict__ srcidx) {
  int e = blockIdx.x * blockDim.x + threadIdx.x;
  if (e < EE) {
    int p = atomicAdd(&cursor[dst[e]], 1);
    srcidx[p] = src[e];
  }
}

// ---------------- fused GCN+SAGE+GAT aggregation + gelu ensemble ---------------
__global__ __launch_bounds__(256) void k_agg1(
    const int* __restrict__ srcidx, const int* __restrict__ offs,
    const int* __restrict__ cnt, const float* __restrict__ H,
    const float2* __restrict__ aux, const float* __restrict__ a_d,
    const float* __restrict__ b_gcn, const float* __restrict__ bl,
    const float* __restrict__ b_gat, const float* __restrict__ w,
    float* __restrict__ ens) {
  int node = (blockIdx.x * blockDim.x + threadIdx.x) >> 6;
  int lane = threadIdx.x & 63;
  if (node >= NN) return;
  int beg = offs[node];
  int c = cnt[node];
  int end = beg + c;
  float2 axd = aux[node];  // {dinv_d, a_s_d}
  float dd = axd.x;
  float a_dd = a_d[node];
  float accg = 0.f, accs = 0.f, acca = 0.f, dg = 0.f;
  int p = beg;
  for (; p + 1 < end; p += 2) {
    int s0 = srcidx[p], s1 = srcidx[p + 1];
    float2 ax0 = aux[s0], ax1 = aux[s1];
    const float* h0 = H + (size_t)s0 * 256;
    const float* h1 = H + (size_t)s1 * 256;
    float g0 = h0[lane], g1 = h1[lane];
    float q0 = h0[64 + lane], q1 = h1[64 + lane];
    float t0 = h0[128 + lane], t1 = h1[128 + lane];
    float ex0 = __expf(leaky02(ax0.y + a_dd));
    float ex1 = __expf(leaky02(ax1.y + a_dd));
    accg = fmaf(g0, ax0.x * dd, accg);
    accg = fmaf(g1, ax1.x * dd, accg);
    accs += q0 + q1;
    acca = fmaf(t0, ex0, acca);
    acca = fmaf(t1, ex1, acca);
    dg += ex0 + ex1;
  }
  if (p < end) {
    int s0 = srcidx[p];
    float2 ax0 = aux[s0];
    const float* h0 = H + (size_t)s0 * 256;
    float ex0 = __expf(leaky02(ax0.y + a_dd));
    accg = fmaf(h0[lane], ax0.x * dd, accg);
    accs += h0[64 + lane];
    acca = fmaf(h0[128 + lane], ex0, acca);
    dg += ex0;
  }
  const float* hd = H + (size_t)node * 256;
  float exl = __expf(leaky02(axd.y + a_dd));
  float g = accg + dd * dd * hd[lane] + b_gcn[lane];
  float sg = accs / fmaxf((float)c, 1.0f) + bl[lane] + hd[192 + lane];
  float ga = (acca + exl * hd[128 + lane]) / (dg + exl + 1e-16f) + b_gat[lane];
  ens[(size_t)node * 64 + lane] =
      w[0] * gelu_exact(g) + w[1] * gelu_exact(sg) + w[2] * gelu_exact(ga);
}

// ---------------- GEMM B: QKVS = ens @ [Wq|Wk|Wv|Wskip] + bias -----------------
__global__ __launch_bounds__(256) void k_gemmB(
    const float* __restrict__ ens, const float* __restrict__ W0,
    const float* __restrict__ W1, const float* __restrict__ W2,
    const float* __restrict__ W3, const float* __restrict__ b0,
    const float* __restrict__ b1, const float* __restrict__ b2,
    const float* __restrict__ b3, float* __restrict__ QKVS) {
  __shared__ float est[64][65];  // [k][r]
  __shared__ float wt[64][40];   // [k][c]
  const int m = blockIdx.y;
  const float* W = (m == 0) ? W0 : (m == 1) ? W1 : (m == 2) ? W2 : W3;
  const float* bias = (m == 0) ? b0 : (m == 1) ? b1 : (m == 2) ? b2 : b3;
  const int rbase = blockIdx.x * 64;
  const int t = threadIdx.x;
  const int r0 = (t >> 3) * 2, c0 = (t & 7) * 5;
  for (int idx = t; idx < 64 * 64; idx += 256) {
    int k = idx & 63, r = idx >> 6;
    int row = rbase + r;
    est[k][r] = (row < NN) ? ens[(size_t)row * HID + k] : 0.f;
  }
  for (int idx = t; idx < 64 * CL; idx += 256) {
    int k = idx / CL, c = idx % CL;
    wt[k][c] = W[k * CL + c];
  }
  __syncthreads();
  float acc[2][5] = {};
#pragma unroll 8
  for (int k = 0; k < 64; ++k) {
    float a[2], b[5];
#pragma unroll
    for (int i = 0; i < 2; ++i) a[i] = est[k][r0 + i];
#pragma unroll
    for (int j = 0; j < 5; ++j) b[j] = wt[k][c0 + j];
#pragma unroll
    for (int i = 0; i < 2; ++i)
#pragma unroll
      for (int j = 0; j < 5; ++j) acc[i][j] = fmaf(a[i], b[j], acc[i][j]);
  }
#pragma unroll
  for (int i = 0; i < 2; ++i) {
    int row = rbase + r0 + i;
    if (row < NN) {
#pragma unroll
      for (int j = 0; j < 5; ++j)
        QKVS[(size_t)row * 160 + m * CL + c0 + j] = acc[i][j] + bias[c0 + j];
    }
  }
}

// ---------------- fused transformer aggregation + log_softmax ------------------
__global__ __launch_bounds__(256) void k_agg2(
    const int* __restrict__ srcidx, const int* __restrict__ offs,
    const int* __restrict__ cnt, const float* __restrict__ QKVS,
    float* __restrict__ out) {
  int node = (blockIdx.x * blockDim.x + threadIdx.x) >> 6;
  int lane = threadIdx.x & 63;
  if (node >= NN) return;
  bool valid = lane < CL;
  int beg = offs[node];
  int end = beg + cnt[node];
  const float* rd = QKVS + (size_t)node * 160;
  float q = valid ? rd[lane] : 0.f;
  float skip = valid ? rd[120 + lane] : 0.f;
  float den = 0.f, accv = 0.f;
  const float ISQ = 0.15811388300841897f;  // 1/sqrt(40)
  int p = beg;
  for (; p + 1 < end; p += 2) {
    int s0 = srcidx[p], s1 = srcidx[p + 1];
    const float* r0 = QKVS + (size_t)s0 * 160;
    const float* r1 = QKVS + (size_t)s1 * 160;
    float k0 = valid ? r0[40 + lane] : 0.f, v0 = valid ? r0[80 + lane] : 0.f;
    float k1 = valid ? r1[40 + lane] : 0.f, v1 = valid ? r1[80 + lane] : 0.f;
    float e0 = __expf(wave_sum(q * k0) * ISQ);
    float e1 = __expf(wave_sum(q * k1) * ISQ);
    den += e0 + e1;
    accv = fmaf(e0, v0, accv);
    accv = fmaf(e1, v1, accv);
  }
  if (p < end) {
    int s0 = srcidx[p];
    const float* r0 = QKVS + (size_t)s0 * 160;
    float k0 = valid ? r0[40 + lane] : 0.f, v0 = valid ? r0[80 + lane] : 0.f;
    float e0 = __expf(wave_sum(q * k0) * ISQ);
    den += e0;
    accv = fmaf(e0, v0, accv);
  }
  float o = valid ? accv / (den + 1e-16f) + skip : -3.0e38f;
  float m = wave_max(o);
  float eo = valid ? __expf(o - m) : 0.f;
  float ssum = wave_sum(eo);
  if (valid) out[(size_t)node * CL + lane] = o - m - logf(ssum);
}

extern "C" void kernel_launch(void* const* d_in, const int* in_sizes, int n_in,
                              void* d_out, int out_size, void* d_ws,
                              size_t ws_size, hipStream_t stream) {
  const float* x     = (const float*)d_in[0];
  const int*   ei    = (const int*)d_in[1];
  const float* w     = (const float*)d_in[2];
  const float* W_gcn = (const float*)d_in[3];
  const float* b_gcn = (const float*)d_in[4];
  const float* Wl    = (const float*)d_in[5];
  const float* bl    = (const float*)d_in[6];
  const float* Wr    = (const float*)d_in[7];
  const float* W_gat = (const float*)d_in[8];
  const float* att_s = (const float*)d_in[9];
  const float* att_d = (const float*)d_in[10];
  const float* b_gat = (const float*)d_in[11];
  const float* Wq    = (const float*)d_in[12];
  const float* bq    = (const float*)d_in[13];
  const float* Wk    = (const float*)d_in[14];
  const float* bk    = (const float*)d_in[15];
  const float* Wv    = (const float*)d_in[16];
  const float* bv    = (const float*)d_in[17];
  const float* Wsk   = (const float*)d_in[18];
  const float* bsk   = (const float*)d_in[19];
  float* out = (float*)d_out;
  float* ws  = (float*)d_ws;

  const int* src = ei;
  const int* dst = ei + EE;

  // workspace layout
  float*  H      = ws;                            // 256N floats
  float*  ens    = ws + (size_t)256 * NN;         // 64N
  float*  a_s    = ws + (size_t)320 * NN;         // N
  float*  a_d    = ws + (size_t)321 * NN;         // N
  float2* aux    = (float2*)(ws + (size_t)322 * NN);  // N float2 (2N floats)
  float*  qkvs   = ws + (size_t)324 * NN;         // 160N
  int*    ibase  = (int*)(ws + (size_t)484 * NN);
  int*    cnt    = ibase;                         // N
  int*    offs   = ibase + NN;                    // N
  int*    cursor = ibase + 2 * NN;                // N
  int*    srcidx = ibase + 3 * NN;                // EE
  int*    bsum   = ibase + 3 * NN + EE;           // NBLK
  int*    boffs  = bsum + NBLK;                   // NBLK

  hipMemsetAsync(cnt, 0, (size_t)NN * sizeof(int), stream);

  dim3 gA((NN + 63) / 64, 4);
  k_gemmA<<<gA, 256, 0, stream>>>(x, W_gcn, Wl, W_gat, Wr, H);
  k_att<<<(NN + 3) / 4, 256, 0, stream>>>(H, att_s, att_d, a_s, a_d);
  k_hist<<<(EE + 255) / 256, 256, 0, stream>>>(dst, cnt);
  k_bsum<<<NBLK, SCB, 0, stream>>>(cnt, bsum);
  k_bscan<<<1, SCB, 0, stream>>>(bsum, boffs);
  k_apply<<<NBLK, SCB, 0, stream>>>(cnt, boffs, offs, cursor, a_s, aux);
  k_scatter<<<(EE + 255) / 256, 256, 0, stream>>>(src, dst, cursor, srcidx);
  k_agg1<<<(NN + 3) / 4, 256, 0, stream>>>(srcidx, offs, cnt, H, aux, a_d,
                                           b_gcn, bl, b_gat, w, ens);
  dim3 gB((NN + 63) / 64, 4);
  k_gemmB<<<gB, 256, 0, stream>>>(ens, Wq, Wk, Wv, Wsk, bq, bk, bv, bsk, qkvs);
  k_agg2<<<(NN + 3) / 4, 256, 0, stream>>>(srcidx, offs, cnt, qkvs, out);
}

// Round 4
// 396.854 us; speedup vs baseline: 2.3339x; 1.0140x over previous
//
#include <hip/hip_runtime.h>
#include <math.h>

#define NN 50000
#define EE 800000
#define FIN 128
#define HID 64
#define CL 40
#define SCB 256
#define NBLK ((NN + SCB - 1) / SCB)  // 196

typedef unsigned short ushort_t;
typedef unsigned int uint_t;

__device__ __forceinline__ ushort_t f2bf(float f) {
  uint_t u = __float_as_uint(f);
  u = (u + 0x7FFFu + ((u >> 16) & 1u)) >> 16;  // RNE
  return (ushort_t)u;
}
__device__ __forceinline__ float bf2f(ushort_t s) {
  return __uint_as_float(((uint_t)s) << 16);
}

__device__ __forceinline__ float wave_sum(float v) {
#pragma unroll
  for (int off = 32; off > 0; off >>= 1) v += __shfl_xor(v, off, 64);
  return v;
}
__device__ __forceinline__ int wave_sum_i(int v) {
#pragma unroll
  for (int off = 32; off > 0; off >>= 1) v += __shfl_xor(v, off, 64);
  return v;
}
__device__ __forceinline__ float wave_max(float v) {
#pragma unroll
  for (int off = 32; off > 0; off >>= 1) v = fmaxf(v, __shfl_xor(v, off, 64));
  return v;
}
__device__ __forceinline__ float gelu_exact(float x) {
  return 0.5f * x * (1.0f + erff(x * 0.70710678118654752f));
}
__device__ __forceinline__ float leaky02(float x) {
  return x >= 0.f ? x : 0.2f * x;
}

// ---------------- GEMM A: Hb = bf16( x @ [W_gcn | Wl_sage | W_gat | Wr_sage] ) -
// Column order: edge pass gathers blocks 0..2 (gcn|sage|gat); block 3 = root.
__global__ __launch_bounds__(256) void k_gemmA(
    const float* __restrict__ x, const float* __restrict__ W0,
    const float* __restrict__ W1, const float* __restrict__ W2,
    const float* __restrict__ W3, ushort_t* __restrict__ Hb) {
  __shared__ float xst[64][65];  // [k][r] transposed x tile (padded)
  __shared__ float wsm[64][64];  // [k][c]
  const int m = blockIdx.y;
  const float* W = (m == 0) ? W0 : (m == 1) ? W1 : (m == 2) ? W2 : W3;
  const int rbase = blockIdx.x * 64;
  const int t = threadIdx.x;
  const int r0 = (t >> 4) * 4, c0 = (t & 15) * 4;
  float acc[4][4] = {};
  for (int kc = 0; kc < FIN; kc += 64) {
    for (int idx = t; idx < 64 * 64; idx += 256) {
      int k = idx & 63, r = idx >> 6;
      int row = rbase + r;
      xst[k][r] = (row < NN) ? x[(size_t)row * FIN + kc + k] : 0.f;
    }
    for (int idx = t; idx < 64 * 64; idx += 256) {
      int k = idx >> 6, c = idx & 63;
      wsm[k][c] = W[(kc + k) * HID + c];
    }
    __syncthreads();
#pragma unroll 8
    for (int k = 0; k < 64; ++k) {
      float a[4], b[4];
#pragma unroll
      for (int i = 0; i < 4; ++i) a[i] = xst[k][r0 + i];
#pragma unroll
      for (int j = 0; j < 4; ++j) b[j] = wsm[k][c0 + j];
#pragma unroll
      for (int i = 0; i < 4; ++i)
#pragma unroll
        for (int j = 0; j < 4; ++j) acc[i][j] = fmaf(a[i], b[j], acc[i][j]);
    }
    __syncthreads();
  }
#pragma unroll
  for (int i = 0; i < 4; ++i) {
    int row = rbase + r0 + i;
    if (row < NN) {
      ushort4 pk;
      pk.x = f2bf(acc[i][0]);
      pk.y = f2bf(acc[i][1]);
      pk.z = f2bf(acc[i][2]);
      pk.w = f2bf(acc[i][3]);
      *(ushort4*)&Hb[(size_t)row * 256 + m * 64 + c0] = pk;
    }
  }
}

// ---------------- attention scalars (GAT block = cols 128..191) ----------------
__global__ __launch_bounds__(256) void k_att(
    const ushort_t* __restrict__ Hb, const float* __restrict__ att_s,
    const float* __restrict__ att_d, float* __restrict__ a_s,
    float* __restrict__ a_d) {
  int wid = (blockIdx.x * blockDim.x + threadIdx.x) >> 6;
  int lane = threadIdx.x & 63;
  if (wid >= NN) return;
  float h = bf2f(Hb[(size_t)wid * 256 + 128 + lane]);
  float s1 = wave_sum(h * att_s[lane]);
  float s2 = wave_sum(h * att_d[lane]);
  if (lane == 0) { a_s[wid] = s1; a_d[wid] = s2; }
}

// ---------------- histogram of dst ---------------------------------------------
__global__ __launch_bounds__(256) void k_hist(const int* __restrict__ dst,
                                              int* __restrict__ cnt) {
  int e = blockIdx.x * blockDim.x + threadIdx.x;
  if (e < EE) atomicAdd(&cnt[dst[e]], 1);
}

// ---------------- 3-phase parallel exclusive scan ------------------------------
__global__ __launch_bounds__(SCB) void k_bsum(const int* __restrict__ cnt,
                                              int* __restrict__ bsum) {
  __shared__ int wsm[4];
  int i = blockIdx.x * SCB + threadIdx.x;
  int v = (i < NN) ? cnt[i] : 0;
  int s = wave_sum_i(v);
  int lane = threadIdx.x & 63, wv = threadIdx.x >> 6;
  if (lane == 0) wsm[wv] = s;
  __syncthreads();
  if (threadIdx.x == 0) bsum[blockIdx.x] = wsm[0] + wsm[1] + wsm[2] + wsm[3];
}

__global__ __launch_bounds__(SCB) void k_bscan(const int* __restrict__ bsum,
                                               int* __restrict__ boffs) {
  __shared__ int ts[SCB];
  int t = threadIdx.x;
  int v = (t < NBLK) ? bsum[t] : 0;
  ts[t] = v;
  __syncthreads();
  for (int off = 1; off < SCB; off <<= 1) {
    int u = (t >= off) ? ts[t - off] : 0;
    __syncthreads();
    ts[t] += u;
    __syncthreads();
  }
  if (t < NBLK) boffs[t] = ts[t] - v;  // exclusive
}

__global__ __launch_bounds__(SCB) void k_apply(
    const int* __restrict__ cnt, const int* __restrict__ boffs,
    int* __restrict__ offs, int* __restrict__ cursor,
    const float* __restrict__ a_s, float2* __restrict__ aux) {
  __shared__ int ts[SCB];
  int i = blockIdx.x * SCB + threadIdx.x;
  int t = threadIdx.x;
  int v = (i < NN) ? cnt[i] : 0;
  ts[t] = v;
  __syncthreads();
  for (int off = 1; off < SCB; off <<= 1) {
    int u = (t >= off) ? ts[t - off] : 0;
    __syncthreads();
    ts[t] += u;
    __syncthreads();
  }
  if (i < NN) {
    int ex = ts[t] - v + boffs[blockIdx.x];
    offs[i] = ex;
    cursor[i] = ex;
    aux[i] = make_float2(rsqrtf((float)v + 1.0f), a_s[i]);
  }
}

// ---------------- counting-sort scatter: srcidx sorted by dst ------------------
__global__ __launch_bounds__(256) void k_scatter(const int* __restrict__ src,
                                                 const int* __restrict__ dst,
                                                 int* __restrict__ cursor,
                                                 int* __restrict__ srcidx) {
  int e = blockIdx.x * blockDim.x + threadIdx.x;
  if (e < EE) {
    int p = atomicAdd(&cursor[dst[e]], 1);
    srcidx[p] = src[e];
  }
}

// ---------------- fused GCN+SAGE+GAT aggregation + gelu ensemble ---------------
__global__ __launch_bounds__(256) void k_agg1(
    const int* __restrict__ srcidx, const int* __restrict__ offs,
    const int* __restrict__ cnt, const ushort_t* __restrict__ Hb,
    const float2* __restrict__ aux, const float* __restrict__ a_d,
    const float* __restrict__ b_gcn, const float* __restrict__ bl,
    const float* __restrict__ b_gat, const float* __restrict__ w,
    float* __restrict__ ens) {
  int node = (blockIdx.x * blockDim.x + threadIdx.x) >> 6;
  int lane = threadIdx.x & 63;
  if (node >= NN) return;
  int beg = offs[node];
  int c = cnt[node];
  int end = beg + c;
  float2 axd = aux[node];  // {dinv_d, a_s_d}
  float dd = axd.x;
  float a_dd = a_d[node];
  float accg = 0.f, accs = 0.f, acca = 0.f, dg = 0.f;
  int p = beg;
  for (; p + 3 < end; p += 4) {
    int s0 = srcidx[p], s1 = srcidx[p + 1], s2 = srcidx[p + 2],
        s3 = srcidx[p + 3];
    float2 ax0 = aux[s0], ax1 = aux[s1], ax2 = aux[s2], ax3 = aux[s3];
    const ushort_t* h0 = Hb + (size_t)s0 * 256;
    const ushort_t* h1 = Hb + (size_t)s1 * 256;
    const ushort_t* h2 = Hb + (size_t)s2 * 256;
    const ushort_t* h3 = Hb + (size_t)s3 * 256;
    float g0 = bf2f(h0[lane]), g1 = bf2f(h1[lane]);
    float g2 = bf2f(h2[lane]), g3 = bf2f(h3[lane]);
    float q0 = bf2f(h0[64 + lane]), q1 = bf2f(h1[64 + lane]);
    float q2 = bf2f(h2[64 + lane]), q3 = bf2f(h3[64 + lane]);
    float t0 = bf2f(h0[128 + lane]), t1 = bf2f(h1[128 + lane]);
    float t2 = bf2f(h2[128 + lane]), t3 = bf2f(h3[128 + lane]);
    float ex0 = __expf(leaky02(ax0.y + a_dd));
    float ex1 = __expf(leaky02(ax1.y + a_dd));
    float ex2 = __expf(leaky02(ax2.y + a_dd));
    float ex3 = __expf(leaky02(ax3.y + a_dd));
    accg = fmaf(g0, ax0.x * dd, accg);
    accg = fmaf(g1, ax1.x * dd, accg);
    accg = fmaf(g2, ax2.x * dd, accg);
    accg = fmaf(g3, ax3.x * dd, accg);
    accs += (q0 + q1) + (q2 + q3);
    acca = fmaf(t0, ex0, acca);
    acca = fmaf(t1, ex1, acca);
    acca = fmaf(t2, ex2, acca);
    acca = fmaf(t3, ex3, acca);
    dg += (ex0 + ex1) + (ex2 + ex3);
  }
  for (; p < end; ++p) {
    int s0 = srcidx[p];
    float2 ax0 = aux[s0];
    const ushort_t* h0 = Hb + (size_t)s0 * 256;
    float ex0 = __expf(leaky02(ax0.y + a_dd));
    accg = fmaf(bf2f(h0[lane]), ax0.x * dd, accg);
    accs += bf2f(h0[64 + lane]);
    acca = fmaf(bf2f(h0[128 + lane]), ex0, acca);
    dg += ex0;
  }
  const ushort_t* hd = Hb + (size_t)node * 256;
  float exl = __expf(leaky02(axd.y + a_dd));
  float g = accg + dd * dd * bf2f(hd[lane]) + b_gcn[lane];
  float sg = accs / fmaxf((float)c, 1.0f) + bl[lane] + bf2f(hd[192 + lane]);
  float ga = (acca + exl * bf2f(hd[128 + lane])) / (dg + exl + 1e-16f) +
             b_gat[lane];
  ens[(size_t)node * 64 + lane] =
      w[0] * gelu_exact(g) + w[1] * gelu_exact(sg) + w[2] * gelu_exact(ga);
}

// ---------------- GEMM B: QKVSb = bf16( ens @ [Wq|Wk|Wv|Wskip] + bias ) --------
__global__ __launch_bounds__(256) void k_gemmB(
    const float* __restrict__ ens, const float* __restrict__ W0,
    const float* __restrict__ W1, const float* __restrict__ W2,
    const float* __restrict__ W3, const float* __restrict__ b0,
    const float* __restrict__ b1, const float* __restrict__ b2,
    const float* __restrict__ b3, ushort_t* __restrict__ QKVSb) {
  __shared__ float est[64][65];  // [k][r]
  __shared__ float wt[64][40];   // [k][c]
  const int m = blockIdx.y;
  const float* W = (m == 0) ? W0 : (m == 1) ? W1 : (m == 2) ? W2 : W3;
  const float* bias = (m == 0) ? b0 : (m == 1) ? b1 : (m == 2) ? b2 : b3;
  const int rbase = blockIdx.x * 64;
  const int t = threadIdx.x;
  const int r0 = (t >> 3) * 2, c0 = (t & 7) * 5;
  for (int idx = t; idx < 64 * 64; idx += 256) {
    int k = idx & 63, r = idx >> 6;
    int row = rbase + r;
    est[k][r] = (row < NN) ? ens[(size_t)row * HID + k] : 0.f;
  }
  for (int idx = t; idx < 64 * CL; idx += 256) {
    int k = idx / CL, c = idx % CL;
    wt[k][c] = W[k * CL + c];
  }
  __syncthreads();
  float acc[2][5] = {};
#pragma unroll 8
  for (int k = 0; k < 64; ++k) {
    float a[2], b[5];
#pragma unroll
    for (int i = 0; i < 2; ++i) a[i] = est[k][r0 + i];
#pragma unroll
    for (int j = 0; j < 5; ++j) b[j] = wt[k][c0 + j];
#pragma unroll
    for (int i = 0; i < 2; ++i)
#pragma unroll
      for (int j = 0; j < 5; ++j) acc[i][j] = fmaf(a[i], b[j], acc[i][j]);
  }
#pragma unroll
  for (int i = 0; i < 2; ++i) {
    int row = rbase + r0 + i;
    if (row < NN) {
#pragma unroll
      for (int j = 0; j < 5; ++j)
        QKVSb[(size_t)row * 160 + m * CL + c0 + j] =
            f2bf(acc[i][j] + bias[c0 + j]);
    }
  }
}

// ---------------- fused transformer aggregation + log_softmax ------------------
__global__ __launch_bounds__(256) void k_agg2(
    const int* __restrict__ srcidx, const int* __restrict__ offs,
    const int* __restrict__ cnt, const ushort_t* __restrict__ QKVSb,
    float* __restrict__ out) {
  int node = (blockIdx.x * blockDim.x + threadIdx.x) >> 6;
  int lane = threadIdx.x & 63;
  if (node >= NN) return;
  bool valid = lane < CL;
  int beg = offs[node];
  int end = beg + cnt[node];
  const ushort_t* rd = QKVSb + (size_t)node * 160;
  float q = valid ? bf2f(rd[lane]) : 0.f;
  float skip = valid ? bf2f(rd[120 + lane]) : 0.f;
  float den = 0.f, accv = 0.f;
  const float ISQ = 0.15811388300841897f;  // 1/sqrt(40)
  int p = beg;
  for (; p + 1 < end; p += 2) {
    int s0 = srcidx[p], s1 = srcidx[p + 1];
    const ushort_t* r0 = QKVSb + (size_t)s0 * 160;
    const ushort_t* r1 = QKVSb + (size_t)s1 * 160;
    float k0 = valid ? bf2f(r0[40 + lane]) : 0.f;
    float v0 = valid ? bf2f(r0[80 + lane]) : 0.f;
    float k1 = valid ? bf2f(r1[40 + lane]) : 0.f;
    float v1 = valid ? bf2f(r1[80 + lane]) : 0.f;
    float e0 = __expf(wave_sum(q * k0) * ISQ);
    float e1 = __expf(wave_sum(q * k1) * ISQ);
    den += e0 + e1;
    accv = fmaf(e0, v0, accv);
    accv = fmaf(e1, v1, accv);
  }
  if (p < end) {
    int s0 = srcidx[p];
    const ushort_t* r0 = QKVSb + (size_t)s0 * 160;
    float k0 = valid ? bf2f(r0[40 + lane]) : 0.f;
    float v0 = valid ? bf2f(r0[80 + lane]) : 0.f;
    float e0 = __expf(wave_sum(q * k0) * ISQ);
    den += e0;
    accv = fmaf(e0, v0, accv);
  }
  float o = valid ? accv / (den + 1e-16f) + skip : -3.0e38f;
  float m = wave_max(o);
  float eo = valid ? __expf(o - m) : 0.f;
  float ssum = wave_sum(eo);
  if (valid) out[(size_t)node * CL + lane] = o - m - logf(ssum);
}

extern "C" void kernel_launch(void* const* d_in, const int* in_sizes, int n_in,
                              void* d_out, int out_size, void* d_ws,
                              size_t ws_size, hipStream_t stream) {
  const float* x     = (const float*)d_in[0];
  const int*   ei    = (const int*)d_in[1];
  const float* w     = (const float*)d_in[2];
  const float* W_gcn = (const float*)d_in[3];
  const float* b_gcn = (const float*)d_in[4];
  const float* Wl    = (const float*)d_in[5];
  const float* bl    = (const float*)d_in[6];
  const float* Wr    = (const float*)d_in[7];
  const float* W_gat = (const float*)d_in[8];
  const float* att_s = (const float*)d_in[9];
  const float* att_d = (const float*)d_in[10];
  const float* b_gat = (const float*)d_in[11];
  const float* Wq    = (const float*)d_in[12];
  const float* bq    = (const float*)d_in[13];
  const float* Wk    = (const float*)d_in[14];
  const float* bk    = (const float*)d_in[15];
  const float* Wv    = (const float*)d_in[16];
  const float* bv    = (const float*)d_in[17];
  const float* Wsk   = (const float*)d_in[18];
  const float* bsk   = (const float*)d_in[19];
  float* out = (float*)d_out;
  float* ws  = (float*)d_ws;

  const int* src = ei;
  const int* dst = ei + EE;

  // workspace layout (float-unit offsets)
  ushort_t* Hb    = (ushort_t*)ws;                     // 256N shorts (=128N fl)
  float*    ens   = ws + (size_t)128 * NN;             // 64N
  float*    a_s   = ws + (size_t)192 * NN;             // N
  float*    a_d   = ws + (size_t)193 * NN;             // N
  float2*   aux   = (float2*)(ws + (size_t)194 * NN);  // 2N
  ushort_t* qkvsb = (ushort_t*)(ws + (size_t)196 * NN);  // 160N shorts (=80N)
  int*      ibase = (int*)(ws + (size_t)276 * NN);
  int*      cnt    = ibase;                            // N
  int*      offs   = ibase + NN;                       // N
  int*      cursor = ibase + 2 * NN;                   // N
  int*      srcidx = ibase + 3 * NN;                   // EE
  int*      bsum   = ibase + 3 * NN + EE;              // NBLK
  int*      boffs  = bsum + NBLK;                      // NBLK

  hipMemsetAsync(cnt, 0, (size_t)NN * sizeof(int), stream);

  dim3 gA((NN + 63) / 64, 4);
  k_gemmA<<<gA, 256, 0, stream>>>(x, W_gcn, Wl, W_gat, Wr, Hb);
  k_att<<<(NN + 3) / 4, 256, 0, stream>>>(Hb, att_s, att_d, a_s, a_d);
  k_hist<<<(EE + 255) / 256, 256, 0, stream>>>(dst, cnt);
  k_bsum<<<NBLK, SCB, 0, stream>>>(cnt, bsum);
  k_bscan<<<1, SCB, 0, stream>>>(bsum, boffs);
  k_apply<<<NBLK, SCB, 0, stream>>>(cnt, boffs, offs, cursor, a_s, aux);
  k_scatter<<<(EE + 255) / 256, 256, 0, stream>>>(src, dst, cursor, srcidx);
  k_agg1<<<(NN + 3) / 4, 256, 0, stream>>>(srcidx, offs, cnt, Hb, aux, a_d,
                                           b_gcn, bl, b_gat, w, ens);
  dim3 gB((NN + 63) / 64, 4);
  k_gemmB<<<gB, 256, 0, stream>>>(ens, Wq, Wk, Wv, Wsk, bq, bk, bv, bsk, qkvsb);
  k_agg2<<<(NN + 3) / 4, 256, 0, stream>>>(srcidx, offs, cnt, qkvsb, out);
}

// Round 5
// 364.706 us; speedup vs baseline: 2.5397x; 1.0881x over previous
//
#include <hip/hip_runtime.h>
#include <math.h>

#define NN 50000
#define EE 800000
#define FIN 128
#define HID 64
#define CL 40
#define SCB 256
#define NBLK ((NN + SCB - 1) / SCB)  // 196

typedef unsigned short ushort_t;
typedef unsigned int uint_t;

__device__ __forceinline__ ushort_t f2bf(float f) {
  uint_t u = __float_as_uint(f);
  u = (u + 0x7FFFu + ((u >> 16) & 1u)) >> 16;  // RNE
  return (ushort_t)u;
}
__device__ __forceinline__ float bf2f(ushort_t s) {
  return __uint_as_float(((uint_t)s) << 16);
}
// unpack uint = [lo16, hi16] two bf16 -> floats
__device__ __forceinline__ float bflo(uint_t u) {
  return __uint_as_float(u << 16);
}
__device__ __forceinline__ float bfhi(uint_t u) {
  return __uint_as_float(u & 0xFFFF0000u);
}

__device__ __forceinline__ float wave_sum(float v) {
#pragma unroll
  for (int off = 32; off > 0; off >>= 1) v += __shfl_xor(v, off, 64);
  return v;
}
__device__ __forceinline__ int wave_sum_i(int v) {
#pragma unroll
  for (int off = 32; off > 0; off >>= 1) v += __shfl_xor(v, off, 64);
  return v;
}
__device__ __forceinline__ float wave_max(float v) {
#pragma unroll
  for (int off = 32; off > 0; off >>= 1) v = fmaxf(v, __shfl_xor(v, off, 64));
  return v;
}
__device__ __forceinline__ float gelu_exact(float x) {
  return 0.5f * x * (1.0f + erff(x * 0.70710678118654752f));
}
__device__ __forceinline__ float leaky02(float x) {
  return x >= 0.f ? x : 0.2f * x;
}

// ---------------- GEMM A: Hb = bf16( x @ [W_gcn | Wl_sage | W_gat | Wr_sage] ) -
__global__ __launch_bounds__(256) void k_gemmA(
    const float* __restrict__ x, const float* __restrict__ W0,
    const float* __restrict__ W1, const float* __restrict__ W2,
    const float* __restrict__ W3, ushort_t* __restrict__ Hb) {
  __shared__ float xst[64][65];  // [k][r] transposed x tile (padded)
  __shared__ float wsm[64][64];  // [k][c]
  const int m = blockIdx.y;
  const float* W = (m == 0) ? W0 : (m == 1) ? W1 : (m == 2) ? W2 : W3;
  const int rbase = blockIdx.x * 64;
  const int t = threadIdx.x;
  const int r0 = (t >> 4) * 4, c0 = (t & 15) * 4;
  float acc[4][4] = {};
  for (int kc = 0; kc < FIN; kc += 64) {
    for (int idx = t; idx < 64 * 64; idx += 256) {
      int k = idx & 63, r = idx >> 6;
      int row = rbase + r;
      xst[k][r] = (row < NN) ? x[(size_t)row * FIN + kc + k] : 0.f;
    }
    for (int idx = t; idx < 64 * 64; idx += 256) {
      int k = idx >> 6, c = idx & 63;
      wsm[k][c] = W[(kc + k) * HID + c];
    }
    __syncthreads();
#pragma unroll 8
    for (int k = 0; k < 64; ++k) {
      float a[4], b[4];
#pragma unroll
      for (int i = 0; i < 4; ++i) a[i] = xst[k][r0 + i];
#pragma unroll
      for (int j = 0; j < 4; ++j) b[j] = wsm[k][c0 + j];
#pragma unroll
      for (int i = 0; i < 4; ++i)
#pragma unroll
        for (int j = 0; j < 4; ++j) acc[i][j] = fmaf(a[i], b[j], acc[i][j]);
    }
    __syncthreads();
  }
#pragma unroll
  for (int i = 0; i < 4; ++i) {
    int row = rbase + r0 + i;
    if (row < NN) {
      ushort4 pk;
      pk.x = f2bf(acc[i][0]);
      pk.y = f2bf(acc[i][1]);
      pk.z = f2bf(acc[i][2]);
      pk.w = f2bf(acc[i][3]);
      *(ushort4*)&Hb[(size_t)row * 256 + m * 64 + c0] = pk;
    }
  }
}

// ---------------- attention scalars (GAT block = cols 128..191) ----------------
__global__ __launch_bounds__(256) void k_att(
    const ushort_t* __restrict__ Hb, const float* __restrict__ att_s,
    const float* __restrict__ att_d, float* __restrict__ a_s,
    float* __restrict__ a_d) {
  int wid = (blockIdx.x * blockDim.x + threadIdx.x) >> 6;
  int lane = threadIdx.x & 63;
  if (wid >= NN) return;
  float h = bf2f(Hb[(size_t)wid * 256 + 128 + lane]);
  float s1 = wave_sum(h * att_s[lane]);
  float s2 = wave_sum(h * att_d[lane]);
  if (lane == 0) { a_s[wid] = s1; a_d[wid] = s2; }
}

// ---------------- histogram of dst ---------------------------------------------
__global__ __launch_bounds__(256) void k_hist(const int* __restrict__ dst,
                                              int* __restrict__ cnt) {
  int e = blockIdx.x * blockDim.x + threadIdx.x;
  if (e < EE) atomicAdd(&cnt[dst[e]], 1);
}

// ---------------- 3-phase parallel exclusive scan ------------------------------
__global__ __launch_bounds__(SCB) void k_bsum(const int* __restrict__ cnt,
                                              int* __restrict__ bsum) {
  __shared__ int wsm[4];
  int i = blockIdx.x * SCB + threadIdx.x;
  int v = (i < NN) ? cnt[i] : 0;
  int s = wave_sum_i(v);
  int lane = threadIdx.x & 63, wv = threadIdx.x >> 6;
  if (lane == 0) wsm[wv] = s;
  __syncthreads();
  if (threadIdx.x == 0) bsum[blockIdx.x] = wsm[0] + wsm[1] + wsm[2] + wsm[3];
}

__global__ __launch_bounds__(SCB) void k_bscan(const int* __restrict__ bsum,
                                               int* __restrict__ boffs) {
  __shared__ int ts[SCB];
  int t = threadIdx.x;
  int v = (t < NBLK) ? bsum[t] : 0;
  ts[t] = v;
  __syncthreads();
  for (int off = 1; off < SCB; off <<= 1) {
    int u = (t >= off) ? ts[t - off] : 0;
    __syncthreads();
    ts[t] += u;
    __syncthreads();
  }
  if (t < NBLK) boffs[t] = ts[t] - v;  // exclusive
}

__global__ __launch_bounds__(SCB) void k_apply(
    const int* __restrict__ cnt, const int* __restrict__ boffs,
    int* __restrict__ offs, int* __restrict__ cursor,
    const float* __restrict__ a_s, float2* __restrict__ aux) {
  __shared__ int ts[SCB];
  int i = blockIdx.x * SCB + threadIdx.x;
  int t = threadIdx.x;
  int v = (i < NN) ? cnt[i] : 0;
  ts[t] = v;
  __syncthreads();
  for (int off = 1; off < SCB; off <<= 1) {
    int u = (t >= off) ? ts[t - off] : 0;
    __syncthreads();
    ts[t] += u;
    __syncthreads();
  }
  if (i < NN) {
    int ex = ts[t] - v + boffs[blockIdx.x];
    offs[i] = ex;
    cursor[i] = ex;
    aux[i] = make_float2(rsqrtf((float)v + 1.0f), a_s[i]);
  }
}

// ---------------- counting-sort scatter: src + dst sorted by dst ---------------
__global__ __launch_bounds__(256) void k_scatter(const int* __restrict__ src,
                                                 const int* __restrict__ dst,
                                                 int* __restrict__ cursor,
                                                 int* __restrict__ srcidx,
                                                 int* __restrict__ dsts) {
  int e = blockIdx.x * blockDim.x + threadIdx.x;
  if (e < EE) {
    int d = dst[e];
    int p = atomicAdd(&cursor[d], 1);
    srcidx[p] = src[e];
    dsts[p] = d;
  }
}

// ---------------- fused GCN+SAGE+GAT aggregation + gelu ensemble ---------------
__global__ __launch_bounds__(256) void k_agg1(
    const int* __restrict__ srcidx, const int* __restrict__ offs,
    const int* __restrict__ cnt, const ushort_t* __restrict__ Hb,
    const float2* __restrict__ aux, const float* __restrict__ a_d,
    const float* __restrict__ b_gcn, const float* __restrict__ bl,
    const float* __restrict__ b_gat, const float* __restrict__ w,
    float* __restrict__ ens) {
  int node = (blockIdx.x * blockDim.x + threadIdx.x) >> 6;
  int lane = threadIdx.x & 63;
  if (node >= NN) return;
  int beg = offs[node];
  int c = cnt[node];
  int end = beg + c;
  float2 axd = aux[node];  // {dinv_d, a_s_d}
  float dd = axd.x;
  float a_dd = a_d[node];
  float accg = 0.f, accs = 0.f, acca = 0.f, dg = 0.f;
  int p = beg;
  for (; p + 3 < end; p += 4) {
    int s0 = srcidx[p], s1 = srcidx[p + 1], s2 = srcidx[p + 2],
        s3 = srcidx[p + 3];
    float2 ax0 = aux[s0], ax1 = aux[s1], ax2 = aux[s2], ax3 = aux[s3];
    const ushort_t* h0 = Hb + (size_t)s0 * 256;
    const ushort_t* h1 = Hb + (size_t)s1 * 256;
    const ushort_t* h2 = Hb + (size_t)s2 * 256;
    const ushort_t* h3 = Hb + (size_t)s3 * 256;
    float g0 = bf2f(h0[lane]), g1 = bf2f(h1[lane]);
    float g2 = bf2f(h2[lane]), g3 = bf2f(h3[lane]);
    float q0 = bf2f(h0[64 + lane]), q1 = bf2f(h1[64 + lane]);
    float q2 = bf2f(h2[64 + lane]), q3 = bf2f(h3[64 + lane]);
    float t0 = bf2f(h0[128 + lane]), t1 = bf2f(h1[128 + lane]);
    float t2 = bf2f(h2[128 + lane]), t3 = bf2f(h3[128 + lane]);
    float ex0 = __expf(leaky02(ax0.y + a_dd));
    float ex1 = __expf(leaky02(ax1.y + a_dd));
    float ex2 = __expf(leaky02(ax2.y + a_dd));
    float ex3 = __expf(leaky02(ax3.y + a_dd));
    accg = fmaf(g0, ax0.x * dd, accg);
    accg = fmaf(g1, ax1.x * dd, accg);
    accg = fmaf(g2, ax2.x * dd, accg);
    accg = fmaf(g3, ax3.x * dd, accg);
    accs += (q0 + q1) + (q2 + q3);
    acca = fmaf(t0, ex0, acca);
    acca = fmaf(t1, ex1, acca);
    acca = fmaf(t2, ex2, acca);
    acca = fmaf(t3, ex3, acca);
    dg += (ex0 + ex1) + (ex2 + ex3);
  }
  for (; p < end; ++p) {
    int s0 = srcidx[p];
    float2 ax0 = aux[s0];
    const ushort_t* h0 = Hb + (size_t)s0 * 256;
    float ex0 = __expf(leaky02(ax0.y + a_dd));
    accg = fmaf(bf2f(h0[lane]), ax0.x * dd, accg);
    accs += bf2f(h0[64 + lane]);
    acca = fmaf(bf2f(h0[128 + lane]), ex0, acca);
    dg += ex0;
  }
  const ushort_t* hd = Hb + (size_t)node * 256;
  float exl = __expf(leaky02(axd.y + a_dd));
  float g = accg + dd * dd * bf2f(hd[lane]) + b_gcn[lane];
  float sg = accs / fmaxf((float)c, 1.0f) + bl[lane] + bf2f(hd[192 + lane]);
  float ga = (acca + exl * bf2f(hd[128 + lane])) / (dg + exl + 1e-16f) +
             b_gat[lane];
  ens[(size_t)node * 64 + lane] =
      w[0] * gelu_exact(g) + w[1] * gelu_exact(sg) + w[2] * gelu_exact(ga);
}

// ---------------- GEMM B: QKVSb = bf16( ens @ [Wq|Wk|Wv|Wskip] + bias ) --------
__global__ __launch_bounds__(256) void k_gemmB(
    const float* __restrict__ ens, const float* __restrict__ W0,
    const float* __restrict__ W1, const float* __restrict__ W2,
    const float* __restrict__ W3, const float* __restrict__ b0,
    const float* __restrict__ b1, const float* __restrict__ b2,
    const float* __restrict__ b3, ushort_t* __restrict__ QKVSb) {
  __shared__ float est[64][65];  // [k][r]
  __shared__ float wt[64][40];   // [k][c]
  const int m = blockIdx.y;
  const float* W = (m == 0) ? W0 : (m == 1) ? W1 : (m == 2) ? W2 : W3;
  const float* bias = (m == 0) ? b0 : (m == 1) ? b1 : (m == 2) ? b2 : b3;
  const int rbase = blockIdx.x * 64;
  const int t = threadIdx.x;
  const int r0 = (t >> 3) * 2, c0 = (t & 7) * 5;
  for (int idx = t; idx < 64 * 64; idx += 256) {
    int k = idx & 63, r = idx >> 6;
    int row = rbase + r;
    est[k][r] = (row < NN) ? ens[(size_t)row * HID + k] : 0.f;
  }
  for (int idx = t; idx < 64 * CL; idx += 256) {
    int k = idx / CL, c = idx % CL;
    wt[k][c] = W[k * CL + c];
  }
  __syncthreads();
  float acc[2][5] = {};
#pragma unroll 8
  for (int k = 0; k < 64; ++k) {
    float a[2], b[5];
#pragma unroll
    for (int i = 0; i < 2; ++i) a[i] = est[k][r0 + i];
#pragma unroll
    for (int j = 0; j < 5; ++j) b[j] = wt[k][c0 + j];
#pragma unroll
    for (int i = 0; i < 2; ++i)
#pragma unroll
      for (int j = 0; j < 5; ++j) acc[i][j] = fmaf(a[i], b[j], acc[i][j]);
  }
#pragma unroll
  for (int i = 0; i < 2; ++i) {
    int row = rbase + r0 + i;
    if (row < NN) {
#pragma unroll
      for (int j = 0; j < 5; ++j)
        QKVSb[(size_t)row * 160 + m * CL + c0 + j] =
            f2bf(acc[i][j] + bias[c0 + j]);
    }
  }
}

// ---------------- edge-parallel transformer scores (8 lanes/edge) --------------
__global__ __launch_bounds__(256) void k_score(
    const int* __restrict__ srcidx, const int* __restrict__ dsts,
    const ushort_t* __restrict__ QKVSb, float* __restrict__ escore) {
  int p = (blockIdx.x * 256 + threadIdx.x) >> 3;
  int l = threadIdx.x & 7;
  if (p >= EE) return;
  int s = srcidx[p], d = dsts[p];
  float part = 0.f;
  if (l < 5) {
    const uint4 qv = *(const uint4*)(QKVSb + (size_t)d * 160 + l * 8);
    const uint4 kv = *(const uint4*)(QKVSb + (size_t)s * 160 + 40 + l * 8);
    part = bflo(qv.x) * bflo(kv.x);
    part = fmaf(bfhi(qv.x), bfhi(kv.x), part);
    part = fmaf(bflo(qv.y), bflo(kv.y), part);
    part = fmaf(bfhi(qv.y), bfhi(kv.y), part);
    part = fmaf(bflo(qv.z), bflo(kv.z), part);
    part = fmaf(bfhi(qv.z), bfhi(kv.z), part);
    part = fmaf(bflo(qv.w), bflo(kv.w), part);
    part = fmaf(bfhi(qv.w), bfhi(kv.w), part);
  }
  part += __shfl_xor(part, 1, 64);
  part += __shfl_xor(part, 2, 64);
  part += __shfl_xor(part, 4, 64);
  if (l == 0) escore[p] = __expf(part * 0.15811388300841897f);
}

// ---------------- transformer aggregation + log_softmax (no reductions) --------
__global__ __launch_bounds__(256) void k_agg2(
    const int* __restrict__ srcidx, const int* __restrict__ offs,
    const int* __restrict__ cnt, const ushort_t* __restrict__ QKVSb,
    const float* __restrict__ escore, float* __restrict__ out) {
  int node = (blockIdx.x * blockDim.x + threadIdx.x) >> 6;
  int lane = threadIdx.x & 63;
  if (node >= NN) return;
  bool valid = lane < CL;
  int beg = offs[node];
  int end = beg + cnt[node];
  float den = 0.f, accv = 0.f;
  int p = beg;
  for (; p + 3 < end; p += 4) {
    int s0 = srcidx[p], s1 = srcidx[p + 1], s2 = srcidx[p + 2],
        s3 = srcidx[p + 3];
    float e0 = escore[p], e1 = escore[p + 1], e2 = escore[p + 2],
          e3 = escore[p + 3];
    float v0 = valid ? bf2f(QKVSb[(size_t)s0 * 160 + 80 + lane]) : 0.f;
    float v1 = valid ? bf2f(QKVSb[(size_t)s1 * 160 + 80 + lane]) : 0.f;
    float v2 = valid ? bf2f(QKVSb[(size_t)s2 * 160 + 80 + lane]) : 0.f;
    float v3 = valid ? bf2f(QKVSb[(size_t)s3 * 160 + 80 + lane]) : 0.f;
    accv = fmaf(e0, v0, accv);
    accv = fmaf(e1, v1, accv);
    accv = fmaf(e2, v2, accv);
    accv = fmaf(e3, v3, accv);
    den += (e0 + e1) + (e2 + e3);
  }
  for (; p < end; ++p) {
    int s0 = srcidx[p];
    float e0 = escore[p];
    float v0 = valid ? bf2f(QKVSb[(size_t)s0 * 160 + 80 + lane]) : 0.f;
    accv = fmaf(e0, v0, accv);
    den += e0;
  }
  const ushort_t* rd = QKVSb + (size_t)node * 160;
  float skip = valid ? bf2f(rd[120 + lane]) : 0.f;
  float o = valid ? accv / (den + 1e-16f) + skip : -3.0e38f;
  float m = wave_max(o);
  float eo = valid ? __expf(o - m) : 0.f;
  float ssum = wave_sum(eo);
  if (valid) out[(size_t)node * CL + lane] = o - m - logf(ssum);
}

extern "C" void kernel_launch(void* const* d_in, const int* in_sizes, int n_in,
                              void* d_out, int out_size, void* d_ws,
                              size_t ws_size, hipStream_t stream) {
  const float* x     = (const float*)d_in[0];
  const int*   ei    = (const int*)d_in[1];
  const float* w     = (const float*)d_in[2];
  const float* W_gcn = (const float*)d_in[3];
  const float* b_gcn = (const float*)d_in[4];
  const float* Wl    = (const float*)d_in[5];
  const float* bl    = (const float*)d_in[6];
  const float* Wr    = (const float*)d_in[7];
  const float* W_gat = (const float*)d_in[8];
  const float* att_s = (const float*)d_in[9];
  const float* att_d = (const float*)d_in[10];
  const float* b_gat = (const float*)d_in[11];
  const float* Wq    = (const float*)d_in[12];
  const float* bq    = (const float*)d_in[13];
  const float* Wk    = (const float*)d_in[14];
  const float* bk    = (const float*)d_in[15];
  const float* Wv    = (const float*)d_in[16];
  const float* bv    = (const float*)d_in[17];
  const float* Wsk   = (const float*)d_in[18];
  const float* bsk   = (const float*)d_in[19];
  float* out = (float*)d_out;
  float* ws  = (float*)d_ws;

  const int* src = ei;
  const int* dst = ei + EE;

  // workspace layout (float-unit offsets)
  ushort_t* Hb    = (ushort_t*)ws;                     // 256N shorts (=128N fl)
  float*    ens   = ws + (size_t)128 * NN;             // 64N
  float*    a_s   = ws + (size_t)192 * NN;             // N
  float*    a_d   = ws + (size_t)193 * NN;             // N
  float2*   aux   = (float2*)(ws + (size_t)194 * NN);  // 2N
  ushort_t* qkvsb = (ushort_t*)(ws + (size_t)196 * NN);  // 160N shorts (=80N)
  float*    escore = ws + (size_t)276 * NN;            // EE
  int*      ibase = (int*)(ws + (size_t)276 * NN + EE);
  int*      cnt    = ibase;                            // N
  int*      offs   = ibase + NN;                       // N
  int*      cursor = ibase + 2 * NN;                   // N
  int*      srcidx = ibase + 3 * NN;                   // EE
  int*      dsts   = ibase + 3 * NN + EE;              // EE
  int*      bsum   = ibase + 3 * NN + 2 * EE;          // NBLK
  int*      boffs  = bsum + NBLK;                      // NBLK

  hipMemsetAsync(cnt, 0, (size_t)NN * sizeof(int), stream);

  dim3 gA((NN + 63) / 64, 4);
  k_gemmA<<<gA, 256, 0, stream>>>(x, W_gcn, Wl, W_gat, Wr, Hb);
  k_att<<<(NN + 3) / 4, 256, 0, stream>>>(Hb, att_s, att_d, a_s, a_d);
  k_hist<<<(EE + 255) / 256, 256, 0, stream>>>(dst, cnt);
  k_bsum<<<NBLK, SCB, 0, stream>>>(cnt, bsum);
  k_bscan<<<1, SCB, 0, stream>>>(bsum, boffs);
  k_apply<<<NBLK, SCB, 0, stream>>>(cnt, boffs, offs, cursor, a_s, aux);
  k_scatter<<<(EE + 255) / 256, 256, 0, stream>>>(src, dst, cursor, srcidx,
                                                  dsts);
  k_agg1<<<(NN + 3) / 4, 256, 0, stream>>>(srcidx, offs, cnt, Hb, aux, a_d,
                                           b_gcn, bl, b_gat, w, ens);
  dim3 gB((NN + 63) / 64, 4);
  k_gemmB<<<gB, 256, 0, stream>>>(ens, Wq, Wk, Wv, Wsk, bq, bk, bv, bsk, qkvsb);
  k_score<<<(EE * 8 + 255) / 256, 256, 0, stream>>>(srcidx, dsts, qkvsb,
                                                    escore);
  k_agg2<<<(NN + 3) / 4, 256, 0, stream>>>(srcidx, offs, cnt, qkvsb, escore,
                                           out);
}

// Round 6
// 285.001 us; speedup vs baseline: 3.2499x; 1.2797x over previous
//
#include <hip/hip_runtime.h>
#include <math.h>

#define NN 50000
#define EE 800000
#define FIN 128
#define HID 64
#define CL 40
#define SCB 256
#define NBLK ((NN + SCB - 1) / SCB)  // 196

typedef unsigned short ushort_t;
typedef unsigned int uint_t;
typedef float f32x4 __attribute__((ext_vector_type(4)));
typedef short s16x8 __attribute__((ext_vector_type(8)));

__device__ __forceinline__ ushort_t f2bf(float f) {
  uint_t u = __float_as_uint(f);
  u = (u + 0x7FFFu + ((u >> 16) & 1u)) >> 16;  // RNE
  return (ushort_t)u;
}
__device__ __forceinline__ float bf2f(ushort_t s) {
  return __uint_as_float(((uint_t)s) << 16);
}
__device__ __forceinline__ float bflo(uint_t u) {
  return __uint_as_float(u << 16);
}
__device__ __forceinline__ float bfhi(uint_t u) {
  return __uint_as_float(u & 0xFFFF0000u);
}

__device__ __forceinline__ float wave_sum(float v) {
#pragma unroll
  for (int off = 32; off > 0; off >>= 1) v += __shfl_xor(v, off, 64);
  return v;
}
__device__ __forceinline__ int wave_sum_i(int v) {
#pragma unroll
  for (int off = 32; off > 0; off >>= 1) v += __shfl_xor(v, off, 64);
  return v;
}
__device__ __forceinline__ float wave_max(float v) {
#pragma unroll
  for (int off = 32; off > 0; off >>= 1) v = fmaxf(v, __shfl_xor(v, off, 64));
  return v;
}
__device__ __forceinline__ float gelu_exact(float x) {
  return 0.5f * x * (1.0f + erff(x * 0.70710678118654752f));
}
__device__ __forceinline__ float leaky02(float x) {
  return x >= 0.f ? x : 0.2f * x;
}

// ---------------- prep: cast x to bf16 -----------------------------------------
__global__ __launch_bounds__(256) void k_castx(const float* __restrict__ x,
                                               ushort_t* __restrict__ xb) {
  int i = blockIdx.x * 256 + threadIdx.x;
  if (i < NN * FIN / 4) {
    float4 v = ((const float4*)x)[i];
    ushort4 o;
    o.x = f2bf(v.x); o.y = f2bf(v.y); o.z = f2bf(v.z); o.w = f2bf(v.w);
    ((ushort4*)xb)[i] = o;
  }
}

// ---------------- prep: transposed bf16 weight tables --------------------------
// WtA[m][c][k] = Wm[k][c]  (m<4, c<64, k<128)   32768 elems
// WtB[c][k]    = Wm2[k][cc] (c<160, k<64)        10240 elems
// bcat[c]      = bias                            160 elems
__global__ __launch_bounds__(256) void k_prepw(
    const float* __restrict__ W0, const float* __restrict__ W1,
    const float* __restrict__ W2, const float* __restrict__ W3,
    const float* __restrict__ Q0, const float* __restrict__ Q1,
    const float* __restrict__ Q2, const float* __restrict__ Q3,
    const float* __restrict__ b0, const float* __restrict__ b1,
    const float* __restrict__ b2, const float* __restrict__ b3,
    ushort_t* __restrict__ WtA, ushort_t* __restrict__ WtB,
    float* __restrict__ bcat) {
  int idx = blockIdx.x * 256 + threadIdx.x;
  if (idx < 32768) {
    int m = idx >> 13, r = idx & 8191, c = r >> 7, k = r & 127;
    const float* W = (m == 0) ? W0 : (m == 1) ? W1 : (m == 2) ? W2 : W3;
    WtA[idx] = f2bf(W[k * HID + c]);
  } else if (idx < 43008) {
    int j = idx - 32768;
    int c = j >> 6, k = j & 63;
    int mm = c / CL, cc = c % CL;
    const float* W = (mm == 0) ? Q0 : (mm == 1) ? Q1 : (mm == 2) ? Q2 : Q3;
    WtB[j] = f2bf(W[k * CL + cc]);
  } else if (idx < 43168) {
    int c = idx - 43008;
    int mm = c / CL, cc = c % CL;
    const float* b = (mm == 0) ? b0 : (mm == 1) ? b1 : (mm == 2) ? b2 : b3;
    bcat[c] = b[cc];
  }
}

// ---------------- MFMA GEMM A: Hb = bf16(x @ [Wgcn|Wl|Wgat|Wr]) ----------------
// grid (ceil(N/64), 4). 4 waves x 16 rows; 64 cols per block (one matrix m).
__global__ __launch_bounds__(256) void k_gemmA(
    const ushort_t* __restrict__ xb, const ushort_t* __restrict__ WtA,
    ushort_t* __restrict__ Hb) {
  __shared__ __align__(16) ushort_t wlds[64 * 136];  // [c][k] padded +8
  const int t = threadIdx.x;
  const int m = blockIdx.y;
  // stage Wt[m] (64x128 bf16) into LDS
  for (int idx = t; idx < 64 * 16; idx += 256) {
    int c = idx >> 4, ch = idx & 15;
    *(uint4*)&wlds[c * 136 + ch * 8] =
        *(const uint4*)(WtA + m * 8192 + c * 128 + ch * 8);
  }
  __syncthreads();
  const int wv = t >> 6, l = t & 63;
  const int lr = l & 15, lg = l >> 4;
  const int rbase = blockIdx.x * 64 + wv * 16;
  int arow = rbase + lr;
  int arowc = arow < NN ? arow : NN - 1;
  const ushort_t* ap = xb + (size_t)arowc * 128 + lg * 8;
  f32x4 acc[4] = {};
#pragma unroll
  for (int ks = 0; ks < 4; ++ks) {
    s16x8 af = *(const s16x8*)(ap + ks * 32);
#pragma unroll
    for (int n = 0; n < 4; ++n) {
      s16x8 bf = *(const s16x8*)&wlds[(n * 16 + lr) * 136 + ks * 32 + lg * 8];
      acc[n] = __builtin_amdgcn_mfma_f32_16x16x32_bf16(af, bf, acc[n], 0, 0, 0);
    }
  }
#pragma unroll
  for (int n = 0; n < 4; ++n) {
#pragma unroll
    for (int j = 0; j < 4; ++j) {
      int orow = rbase + lg * 4 + j;
      if (orow < NN)
        Hb[(size_t)orow * 256 + m * 64 + n * 16 + lr] = f2bf(acc[n][j]);
    }
  }
}

// ---------------- attention scalars (GAT block = cols 128..191) ----------------
__global__ __launch_bounds__(256) void k_att(
    const ushort_t* __restrict__ Hb, const float* __restrict__ att_s,
    const float* __restrict__ att_d, float* __restrict__ a_s,
    float* __restrict__ a_d) {
  int wid = (blockIdx.x * blockDim.x + threadIdx.x) >> 6;
  int lane = threadIdx.x & 63;
  if (wid >= NN) return;
  float h = bf2f(Hb[(size_t)wid * 256 + 128 + lane]);
  float s1 = wave_sum(h * att_s[lane]);
  float s2 = wave_sum(h * att_d[lane]);
  if (lane == 0) { a_s[wid] = s1; a_d[wid] = s2; }
}

// ---------------- histogram of dst ---------------------------------------------
__global__ __launch_bounds__(256) void k_hist(const int* __restrict__ dst,
                                              int* __restrict__ cnt) {
  int e = blockIdx.x * blockDim.x + threadIdx.x;
  if (e < EE) atomicAdd(&cnt[dst[e]], 1);
}

// ---------------- 3-phase parallel exclusive scan ------------------------------
__global__ __launch_bounds__(SCB) void k_bsum(const int* __restrict__ cnt,
                                              int* __restrict__ bsum) {
  __shared__ int wsm[4];
  int i = blockIdx.x * SCB + threadIdx.x;
  int v = (i < NN) ? cnt[i] : 0;
  int s = wave_sum_i(v);
  int lane = threadIdx.x & 63, wv = threadIdx.x >> 6;
  if (lane == 0) wsm[wv] = s;
  __syncthreads();
  if (threadIdx.x == 0) bsum[blockIdx.x] = wsm[0] + wsm[1] + wsm[2] + wsm[3];
}

__global__ __launch_bounds__(SCB) void k_bscan(const int* __restrict__ bsum,
                                               int* __restrict__ boffs) {
  __shared__ int ts[SCB];
  int t = threadIdx.x;
  int v = (t < NBLK) ? bsum[t] : 0;
  ts[t] = v;
  __syncthreads();
  for (int off = 1; off < SCB; off <<= 1) {
    int u = (t >= off) ? ts[t - off] : 0;
    __syncthreads();
    ts[t] += u;
    __syncthreads();
  }
  if (t < NBLK) boffs[t] = ts[t] - v;  // exclusive
}

__global__ __launch_bounds__(SCB) void k_apply(
    const int* __restrict__ cnt, const int* __restrict__ boffs,
    int* __restrict__ offs, int* __restrict__ cursor,
    const float* __restrict__ a_s, float2* __restrict__ aux) {
  __shared__ int ts[SCB];
  int i = blockIdx.x * SCB + threadIdx.x;
  int t = threadIdx.x;
  int v = (i < NN) ? cnt[i] : 0;
  ts[t] = v;
  __syncthreads();
  for (int off = 1; off < SCB; off <<= 1) {
    int u = (t >= off) ? ts[t - off] : 0;
    __syncthreads();
    ts[t] += u;
    __syncthreads();
  }
  if (i < NN) {
    int ex = ts[t] - v + boffs[blockIdx.x];
    offs[i] = ex;
    cursor[i] = ex;
    aux[i] = make_float2(rsqrtf((float)v + 1.0f), a_s[i]);
  }
}

// ---------------- counting-sort scatter: src + dst sorted by dst ---------------
__global__ __launch_bounds__(256) void k_scatter(const int* __restrict__ src,
                                                 const int* __restrict__ dst,
                                                 int* __restrict__ cursor,
                                                 int* __restrict__ srcidx,
                                                 int* __restrict__ dsts) {
  int e = blockIdx.x * blockDim.x + threadIdx.x;
  if (e < EE) {
    int d = dst[e];
    int p = atomicAdd(&cursor[d], 1);
    srcidx[p] = src[e];
    dsts[p] = d;
  }
}

// ---------------- fused GCN+SAGE+GAT aggregation + gelu ensemble ---------------
__global__ __launch_bounds__(256) void k_agg1(
    const int* __restrict__ srcidx, const int* __restrict__ offs,
    const int* __restrict__ cnt, const ushort_t* __restrict__ Hb,
    const float2* __restrict__ aux, const float* __restrict__ a_d,
    const float* __restrict__ b_gcn, const float* __restrict__ bl,
    const float* __restrict__ b_gat, const float* __restrict__ w,
    ushort_t* __restrict__ ensb) {
  int node = (blockIdx.x * blockDim.x + threadIdx.x) >> 6;
  int lane = threadIdx.x & 63;
  if (node >= NN) return;
  int beg = offs[node];
  int c = cnt[node];
  int end = beg + c;
  float2 axd = aux[node];  // {dinv_d, a_s_d}
  float dd = axd.x;
  float a_dd = a_d[node];
  float accg = 0.f, accs = 0.f, acca = 0.f, dg = 0.f;
  int p = beg;
  for (; p + 3 < end; p += 4) {
    int s0 = srcidx[p], s1 = srcidx[p + 1], s2 = srcidx[p + 2],
        s3 = srcidx[p + 3];
    float2 ax0 = aux[s0], ax1 = aux[s1], ax2 = aux[s2], ax3 = aux[s3];
    const ushort_t* h0 = Hb + (size_t)s0 * 256;
    const ushort_t* h1 = Hb + (size_t)s1 * 256;
    const ushort_t* h2 = Hb + (size_t)s2 * 256;
    const ushort_t* h3 = Hb + (size_t)s3 * 256;
    float g0 = bf2f(h0[lane]), g1 = bf2f(h1[lane]);
    float g2 = bf2f(h2[lane]), g3 = bf2f(h3[lane]);
    float q0 = bf2f(h0[64 + lane]), q1 = bf2f(h1[64 + lane]);
    float q2 = bf2f(h2[64 + lane]), q3 = bf2f(h3[64 + lane]);
    float t0 = bf2f(h0[128 + lane]), t1 = bf2f(h1[128 + lane]);
    float t2 = bf2f(h2[128 + lane]), t3 = bf2f(h3[128 + lane]);
    float ex0 = __expf(leaky02(ax0.y + a_dd));
    float ex1 = __expf(leaky02(ax1.y + a_dd));
    float ex2 = __expf(leaky02(ax2.y + a_dd));
    float ex3 = __expf(leaky02(ax3.y + a_dd));
    accg = fmaf(g0, ax0.x * dd, accg);
    accg = fmaf(g1, ax1.x * dd, accg);
    accg = fmaf(g2, ax2.x * dd, accg);
    accg = fmaf(g3, ax3.x * dd, accg);
    accs += (q0 + q1) + (q2 + q3);
    acca = fmaf(t0, ex0, acca);
    acca = fmaf(t1, ex1, acca);
    acca = fmaf(t2, ex2, acca);
    acca = fmaf(t3, ex3, acca);
    dg += (ex0 + ex1) + (ex2 + ex3);
  }
  for (; p < end; ++p) {
    int s0 = srcidx[p];
    float2 ax0 = aux[s0];
    const ushort_t* h0 = Hb + (size_t)s0 * 256;
    float ex0 = __expf(leaky02(ax0.y + a_dd));
    accg = fmaf(bf2f(h0[lane]), ax0.x * dd, accg);
    accs += bf2f(h0[64 + lane]);
    acca = fmaf(bf2f(h0[128 + lane]), ex0, acca);
    dg += ex0;
  }
  const ushort_t* hd = Hb + (size_t)node * 256;
  float exl = __expf(leaky02(axd.y + a_dd));
  float g = accg + dd * dd * bf2f(hd[lane]) + b_gcn[lane];
  float sg = accs / fmaxf((float)c, 1.0f) + bl[lane] + bf2f(hd[192 + lane]);
  float ga = (acca + exl * bf2f(hd[128 + lane])) / (dg + exl + 1e-16f) +
             b_gat[lane];
  ensb[(size_t)node * 64 + lane] =
      f2bf(w[0] * gelu_exact(g) + w[1] * gelu_exact(sg) + w[2] * gelu_exact(ga));
}

// ---------------- MFMA GEMM B: QKVSb = bf16(ens @ [Wq|Wk|Wv|Wskip] + bias) -----
// grid ceil(N/64). 4 waves x 16 rows; 160 cols (10 tiles/wave). K=64.
__global__ __launch_bounds__(256) void k_gemmB(
    const ushort_t* __restrict__ ensb, const ushort_t* __restrict__ WtB,
    const float* __restrict__ bcat, ushort_t* __restrict__ QKVSb) {
  __shared__ __align__(16) ushort_t wb[160 * 72];  // [c][k] padded +8
  __shared__ float bsh[160];
  const int t = threadIdx.x;
  for (int idx = t; idx < 160 * 8; idx += 256) {
    int c = idx >> 3, ch = idx & 7;
    *(uint4*)&wb[c * 72 + ch * 8] = *(const uint4*)(WtB + c * 64 + ch * 8);
  }
  if (t < 160) bsh[t] = bcat[t];
  __syncthreads();
  const int wv = t >> 6, l = t & 63;
  const int lr = l & 15, lg = l >> 4;
  const int rbase = blockIdx.x * 64 + wv * 16;
  int arow = rbase + lr;
  int arowc = arow < NN ? arow : NN - 1;
  const ushort_t* ap = ensb + (size_t)arowc * 64 + lg * 8;
  f32x4 acc[10] = {};
#pragma unroll
  for (int ks = 0; ks < 2; ++ks) {
    s16x8 af = *(const s16x8*)(ap + ks * 32);
#pragma unroll
    for (int n = 0; n < 10; ++n) {
      s16x8 bf = *(const s16x8*)&wb[(n * 16 + lr) * 72 + ks * 32 + lg * 8];
      acc[n] = __builtin_amdgcn_mfma_f32_16x16x32_bf16(af, bf, acc[n], 0, 0, 0);
    }
  }
#pragma unroll
  for (int n = 0; n < 10; ++n) {
    int col = n * 16 + lr;
#pragma unroll
    for (int j = 0; j < 4; ++j) {
      int orow = rbase + lg * 4 + j;
      if (orow < NN)
        QKVSb[(size_t)orow * 160 + col] = f2bf(acc[n][j] + bsh[col]);
    }
  }
}

// ---------------- edge-parallel transformer scores (8 lanes/edge) --------------
__global__ __launch_bounds__(256) void k_score(
    const int* __restrict__ srcidx, const int* __restrict__ dsts,
    const ushort_t* __restrict__ QKVSb, float* __restrict__ escore) {
  int p = (blockIdx.x * 256 + threadIdx.x) >> 3;
  int l = threadIdx.x & 7;
  if (p >= EE) return;
  int s = srcidx[p], d = dsts[p];
  float part = 0.f;
  if (l < 5) {
    const uint4 qv = *(const uint4*)(QKVSb + (size_t)d * 160 + l * 8);
    const uint4 kv = *(const uint4*)(QKVSb + (size_t)s * 160 + 40 + l * 8);
    part = bflo(qv.x) * bflo(kv.x);
    part = fmaf(bfhi(qv.x), bfhi(kv.x), part);
    part = fmaf(bflo(qv.y), bflo(kv.y), part);
    part = fmaf(bfhi(qv.y), bfhi(kv.y), part);
    part = fmaf(bflo(qv.z), bflo(kv.z), part);
    part = fmaf(bfhi(qv.z), bfhi(kv.z), part);
    part = fmaf(bflo(qv.w), bflo(kv.w), part);
    part = fmaf(bfhi(qv.w), bfhi(kv.w), part);
  }
  part += __shfl_xor(part, 1, 64);
  part += __shfl_xor(part, 2, 64);
  part += __shfl_xor(part, 4, 64);
  if (l == 0) escore[p] = __expf(part * 0.15811388300841897f);
}

// ---------------- transformer aggregation + log_softmax (no reductions) --------
__global__ __launch_bounds__(256) void k_agg2(
    const int* __restrict__ srcidx, const int* __restrict__ offs,
    const int* __restrict__ cnt, const ushort_t* __restrict__ QKVSb,
    const float* __restrict__ escore, float* __restrict__ out) {
  int node = (blockIdx.x * blockDim.x + threadIdx.x) >> 6;
  int lane = threadIdx.x & 63;
  if (node >= NN) return;
  bool valid = lane < CL;
  int beg = offs[node];
  int end = beg + cnt[node];
  float den = 0.f, accv = 0.f;
  int p = beg;
  for (; p + 3 < end; p += 4) {
    int s0 = srcidx[p], s1 = srcidx[p + 1], s2 = srcidx[p + 2],
        s3 = srcidx[p + 3];
    float e0 = escore[p], e1 = escore[p + 1], e2 = escore[p + 2],
          e3 = escore[p + 3];
    float v0 = valid ? bf2f(QKVSb[(size_t)s0 * 160 + 80 + lane]) : 0.f;
    float v1 = valid ? bf2f(QKVSb[(size_t)s1 * 160 + 80 + lane]) : 0.f;
    float v2 = valid ? bf2f(QKVSb[(size_t)s2 * 160 + 80 + lane]) : 0.f;
    float v3 = valid ? bf2f(QKVSb[(size_t)s3 * 160 + 80 + lane]) : 0.f;
    accv = fmaf(e0, v0, accv);
    accv = fmaf(e1, v1, accv);
    accv = fmaf(e2, v2, accv);
    accv = fmaf(e3, v3, accv);
    den += (e0 + e1) + (e2 + e3);
  }
  for (; p < end; ++p) {
    int s0 = srcidx[p];
    float e0 = escore[p];
    float v0 = valid ? bf2f(QKVSb[(size_t)s0 * 160 + 80 + lane]) : 0.f;
    accv = fmaf(e0, v0, accv);
    den += e0;
  }
  const ushort_t* rd = QKVSb + (size_t)node * 160;
  float skip = valid ? bf2f(rd[120 + lane]) : 0.f;
  float o = valid ? accv / (den + 1e-16f) + skip : -3.0e38f;
  float m = wave_max(o);
  float eo = valid ? __expf(o - m) : 0.f;
  float ssum = wave_sum(eo);
  if (valid) out[(size_t)node * CL + lane] = o - m - logf(ssum);
}

extern "C" void kernel_launch(void* const* d_in, const int* in_sizes, int n_in,
                              void* d_out, int out_size, void* d_ws,
                              size_t ws_size, hipStream_t stream) {
  const float* x     = (const float*)d_in[0];
  const int*   ei    = (const int*)d_in[1];
  const float* w     = (const float*)d_in[2];
  const float* W_gcn = (const float*)d_in[3];
  const float* b_gcn = (const float*)d_in[4];
  const float* Wl    = (const float*)d_in[5];
  const float* bl    = (const float*)d_in[6];
  const float* Wr    = (const float*)d_in[7];
  const float* W_gat = (const float*)d_in[8];
  const float* att_s = (const float*)d_in[9];
  const float* att_d = (const float*)d_in[10];
  const float* b_gat = (const float*)d_in[11];
  const float* Wq    = (const float*)d_in[12];
  const float* bq    = (const float*)d_in[13];
  const float* Wk    = (const float*)d_in[14];
  const float* bk    = (const float*)d_in[15];
  const float* Wv    = (const float*)d_in[16];
  const float* bv    = (const float*)d_in[17];
  const float* Wsk   = (const float*)d_in[18];
  const float* bsk   = (const float*)d_in[19];
  float* out = (float*)d_out;
  float* ws  = (float*)d_ws;

  const int* src = ei;
  const int* dst = ei + EE;

  // workspace layout (float-unit offsets)
  ushort_t* Hb     = (ushort_t*)ws;                       // 256N ush = 128N fl
  ushort_t* ensb   = (ushort_t*)(ws + (size_t)128 * NN);  // 64N ush = 32N fl
  float*    a_s    = ws + (size_t)160 * NN;               // N
  float*    a_d    = ws + (size_t)161 * NN;               // N
  float2*   aux    = (float2*)(ws + (size_t)162 * NN);    // 2N
  ushort_t* qkvsb  = (ushort_t*)(ws + (size_t)164 * NN);  // 160N ush = 80N fl
  ushort_t* xb     = (ushort_t*)(ws + (size_t)244 * NN);  // 128N ush = 64N fl
  ushort_t* WtA    = (ushort_t*)(ws + (size_t)308 * NN);  // 32768 ush
  ushort_t* WtB    = (ushort_t*)(ws + (size_t)308 * NN + 16384);  // 10240 ush
  float*    bcat   = ws + (size_t)308 * NN + 21504;       // 160 fl
  float*    escore = ws + (size_t)308 * NN + 21664;       // EE fl
  int*      ibase  = (int*)(ws + (size_t)308 * NN + 21664 + EE);
  int*      cnt    = ibase;                               // N
  int*      offs   = ibase + NN;                          // N
  int*      cursor = ibase + 2 * NN;                      // N
  int*      srcidx = ibase + 3 * NN;                      // EE
  int*      dsts   = ibase + 3 * NN + EE;                 // EE
  int*      bsum   = ibase + 3 * NN + 2 * EE;             // NBLK
  int*      boffs  = bsum + NBLK;                         // NBLK

  hipMemsetAsync(cnt, 0, (size_t)NN * sizeof(int), stream);

  k_castx<<<(NN * FIN / 4 + 255) / 256, 256, 0, stream>>>(x, xb);
  k_prepw<<<(43168 + 255) / 256, 256, 0, stream>>>(
      W_gcn, Wl, W_gat, Wr, Wq, Wk, Wv, Wsk, bq, bk, bv, bsk, WtA, WtB, bcat);

  dim3 gA((NN + 63) / 64, 4);
  k_gemmA<<<gA, 256, 0, stream>>>(xb, WtA, Hb);
  k_att<<<(NN + 3) / 4, 256, 0, stream>>>(Hb, att_s, att_d, a_s, a_d);
  k_hist<<<(EE + 255) / 256, 256, 0, stream>>>(dst, cnt);
  k_bsum<<<NBLK, SCB, 0, stream>>>(cnt, bsum);
  k_bscan<<<1, SCB, 0, stream>>>(bsum, boffs);
  k_apply<<<NBLK, SCB, 0, stream>>>(cnt, boffs, offs, cursor, a_s, aux);
  k_scatter<<<(EE + 255) / 256, 256, 0, stream>>>(src, dst, cursor, srcidx,
                                                  dsts);
  k_agg1<<<(NN + 3) / 4, 256, 0, stream>>>(srcidx, offs, cnt, Hb, aux, a_d,
                                           b_gcn, bl, b_gat, w, ensb);
  k_gemmB<<<(NN + 63) / 64, 256, 0, stream>>>(ensb, WtB, bcat, qkvsb);
  k_score<<<(EE * 8 + 255) / 256, 256, 0, stream>>>(srcidx, dsts, qkvsb,
                                                    escore);
  k_agg2<<<(NN + 3) / 4, 256, 0, stream>>>(srcidx, offs, cnt, qkvsb, escore,
                                           out);
}

// Round 7
// 249.594 us; speedup vs baseline: 3.7109x; 1.1419x over previous
//
#include <hip/hip_runtime.h>
#include <math.h>

#define NN 50000
#define EE 800000
#define FIN 128
#define HID 64
#define CL 40
#define SCB 256
#define NBLK ((NN + SCB - 1) / SCB)  // 196

typedef unsigned short ushort_t;
typedef unsigned int uint_t;
typedef float f32x4 __attribute__((ext_vector_type(4)));
typedef short s16x8 __attribute__((ext_vector_type(8)));

__device__ __forceinline__ ushort_t f2bf(float f) {
  uint_t u = __float_as_uint(f);
  u = (u + 0x7FFFu + ((u >> 16) & 1u)) >> 16;  // RNE
  return (ushort_t)u;
}
__device__ __forceinline__ uint_t f2bf2(float lo, float hi) {
  return (uint_t)f2bf(lo) | ((uint_t)f2bf(hi) << 16);
}
__device__ __forceinline__ float bf2f(ushort_t s) {
  return __uint_as_float(((uint_t)s) << 16);
}
__device__ __forceinline__ float bflo(uint_t u) {
  return __uint_as_float(u << 16);
}
__device__ __forceinline__ float bfhi(uint_t u) {
  return __uint_as_float(u & 0xFFFF0000u);
}

__device__ __forceinline__ float wave_sum(float v) {
#pragma unroll
  for (int off = 32; off > 0; off >>= 1) v += __shfl_xor(v, off, 64);
  return v;
}
__device__ __forceinline__ int wave_sum_i(int v) {
#pragma unroll
  for (int off = 32; off > 0; off >>= 1) v += __shfl_xor(v, off, 64);
  return v;
}
__device__ __forceinline__ float half_sum(float v) {  // within 32-lane half
#pragma unroll
  for (int off = 16; off > 0; off >>= 1) v += __shfl_xor(v, off, 64);
  return v;
}
__device__ __forceinline__ float half_max(float v) {
#pragma unroll
  for (int off = 16; off > 0; off >>= 1) v = fmaxf(v, __shfl_xor(v, off, 64));
  return v;
}
__device__ __forceinline__ float gelu_exact(float x) {
  return 0.5f * x * (1.0f + erff(x * 0.70710678118654752f));
}
__device__ __forceinline__ float leaky02(float x) {
  return x >= 0.f ? x : 0.2f * x;
}

// ---------------- prep: cast x to bf16 -----------------------------------------
__global__ __launch_bounds__(256) void k_castx(const float* __restrict__ x,
                                               ushort_t* __restrict__ xb) {
  int i = blockIdx.x * 256 + threadIdx.x;
  if (i < NN * FIN / 4) {
    float4 v = ((const float4*)x)[i];
    ushort4 o;
    o.x = f2bf(v.x); o.y = f2bf(v.y); o.z = f2bf(v.z); o.w = f2bf(v.w);
    ((ushort4*)xb)[i] = o;
  }
}

// ---------------- prep: transposed bf16 weight tables --------------------------
__global__ __launch_bounds__(256) void k_prepw(
    const float* __restrict__ W0, const float* __restrict__ W1,
    const float* __restrict__ W2, const float* __restrict__ W3,
    const float* __restrict__ Q0, const float* __restrict__ Q1,
    const float* __restrict__ Q2, const float* __restrict__ Q3,
    const float* __restrict__ b0, const float* __restrict__ b1,
    const float* __restrict__ b2, const float* __restrict__ b3,
    ushort_t* __restrict__ WtA, ushort_t* __restrict__ WtB,
    float* __restrict__ bcat) {
  int idx = blockIdx.x * 256 + threadIdx.x;
  if (idx < 32768) {
    int m = idx >> 13, r = idx & 8191, c = r >> 7, k = r & 127;
    const float* W = (m == 0) ? W0 : (m == 1) ? W1 : (m == 2) ? W2 : W3;
    WtA[idx] = f2bf(W[k * HID + c]);
  } else if (idx < 43008) {
    int j = idx - 32768;
    int c = j >> 6, k = j & 63;
    int mm = c / CL, cc = c % CL;
    const float* W = (mm == 0) ? Q0 : (mm == 1) ? Q1 : (mm == 2) ? Q2 : Q3;
    WtB[j] = f2bf(W[k * CL + cc]);
  } else if (idx < 43168) {
    int c = idx - 43008;
    int mm = c / CL, cc = c % CL;
    const float* b = (mm == 0) ? b0 : (mm == 1) ? b1 : (mm == 2) ? b2 : b3;
    bcat[c] = b[cc];
  }
}

// ---------------- MFMA GEMM A: Hb = bf16(x @ [Wgcn|Wl|Wgat|Wr]) ----------------
__global__ __launch_bounds__(256) void k_gemmA(
    const ushort_t* __restrict__ xb, const ushort_t* __restrict__ WtA,
    ushort_t* __restrict__ Hb) {
  __shared__ __align__(16) ushort_t wlds[64 * 136];  // [c][k] padded +8
  const int t = threadIdx.x;
  const int m = blockIdx.y;
  for (int idx = t; idx < 64 * 16; idx += 256) {
    int c = idx >> 4, ch = idx & 15;
    *(uint4*)&wlds[c * 136 + ch * 8] =
        *(const uint4*)(WtA + m * 8192 + c * 128 + ch * 8);
  }
  __syncthreads();
  const int wv = t >> 6, l = t & 63;
  const int lr = l & 15, lg = l >> 4;
  const int rbase = blockIdx.x * 64 + wv * 16;
  int arow = rbase + lr;
  int arowc = arow < NN ? arow : NN - 1;
  const ushort_t* ap = xb + (size_t)arowc * 128 + lg * 8;
  f32x4 acc[4] = {};
#pragma unroll
  for (int ks = 0; ks < 4; ++ks) {
    s16x8 af = *(const s16x8*)(ap + ks * 32);
#pragma unroll
    for (int n = 0; n < 4; ++n) {
      s16x8 bf = *(const s16x8*)&wlds[(n * 16 + lr) * 136 + ks * 32 + lg * 8];
      acc[n] = __builtin_amdgcn_mfma_f32_16x16x32_bf16(af, bf, acc[n], 0, 0, 0);
    }
  }
#pragma unroll
  for (int n = 0; n < 4; ++n) {
#pragma unroll
    for (int j = 0; j < 4; ++j) {
      int orow = rbase + lg * 4 + j;
      if (orow < NN)
        Hb[(size_t)orow * 256 + m * 64 + n * 16 + lr] = f2bf(acc[n][j]);
    }
  }
}

// ---------------- attention scalars (GAT block = cols 128..191) ----------------
__global__ __launch_bounds__(256) void k_att(
    const ushort_t* __restrict__ Hb, const float* __restrict__ att_s,
    const float* __restrict__ att_d, float* __restrict__ a_s,
    float* __restrict__ a_d) {
  int wid = (blockIdx.x * blockDim.x + threadIdx.x) >> 6;
  int lane = threadIdx.x & 63;
  if (wid >= NN) return;
  float h = bf2f(Hb[(size_t)wid * 256 + 128 + lane]);
  float s1 = wave_sum(h * att_s[lane]);
  float s2 = wave_sum(h * att_d[lane]);
  if (lane == 0) { a_s[wid] = s1; a_d[wid] = s2; }
}

// ---------------- histogram of dst ---------------------------------------------
__global__ __launch_bounds__(256) void k_hist(const int* __restrict__ dst,
                                              int* __restrict__ cnt) {
  int e = blockIdx.x * blockDim.x + threadIdx.x;
  if (e < EE) atomicAdd(&cnt[dst[e]], 1);
}

// ---------------- 3-phase parallel exclusive scan ------------------------------
__global__ __launch_bounds__(SCB) void k_bsum(const int* __restrict__ cnt,
                                              int* __restrict__ bsum) {
  __shared__ int wsm[4];
  int i = blockIdx.x * SCB + threadIdx.x;
  int v = (i < NN) ? cnt[i] : 0;
  int s = wave_sum_i(v);
  int lane = threadIdx.x & 63, wv = threadIdx.x >> 6;
  if (lane == 0) wsm[wv] = s;
  __syncthreads();
  if (threadIdx.x == 0) bsum[blockIdx.x] = wsm[0] + wsm[1] + wsm[2] + wsm[3];
}

__global__ __launch_bounds__(SCB) void k_bscan(const int* __restrict__ bsum,
                                               int* __restrict__ boffs) {
  __shared__ int ts[SCB];
  int t = threadIdx.x;
  int v = (t < NBLK) ? bsum[t] : 0;
  ts[t] = v;
  __syncthreads();
  for (int off = 1; off < SCB; off <<= 1) {
    int u = (t >= off) ? ts[t - off] : 0;
    __syncthreads();
    ts[t] += u;
    __syncthreads();
  }
  if (t < NBLK) boffs[t] = ts[t] - v;  // exclusive
}

__global__ __launch_bounds__(SCB) void k_apply(
    const int* __restrict__ cnt, const int* __restrict__ boffs,
    int* __restrict__ offs, int* __restrict__ cursor,
    const float* __restrict__ a_s, float2* __restrict__ aux) {
  __shared__ int ts[SCB];
  int i = blockIdx.x * SCB + threadIdx.x;
  int t = threadIdx.x;
  int v = (i < NN) ? cnt[i] : 0;
  ts[t] = v;
  __syncthreads();
  for (int off = 1; off < SCB; off <<= 1) {
    int u = (t >= off) ? ts[t - off] : 0;
    __syncthreads();
    ts[t] += u;
    __syncthreads();
  }
  if (i < NN) {
    int ex = ts[t] - v + boffs[blockIdx.x];
    offs[i] = ex;
    cursor[i] = ex;
    aux[i] = make_float2(rsqrtf((float)v + 1.0f), a_s[i]);
  }
}

// ---------------- counting-sort scatter: src + dst sorted by dst ---------------
__global__ __launch_bounds__(256) void k_scatter(const int* __restrict__ src,
                                                 const int* __restrict__ dst,
                                                 int* __restrict__ cursor,
                                                 int* __restrict__ srcidx,
                                                 int* __restrict__ dsts) {
  int e = blockIdx.x * blockDim.x + threadIdx.x;
  if (e < EE) {
    int d = dst[e];
    int p = atomicAdd(&cursor[d], 1);
    srcidx[p] = src[e];
    dsts[p] = d;
  }
}

// ---------------- fused GCN+SAGE+GAT aggregation + gelu ensemble ---------------
// 1 node/wave; two 32-lane halves each process alternating edges; lanes load
// packed uint (2 bf16 feats). Accumulators 2-wide; halves folded via shfl.
__global__ __launch_bounds__(256) void k_agg1(
    const int* __restrict__ srcidx, const int* __restrict__ offs,
    const int* __restrict__ cnt, const ushort_t* __restrict__ Hb,
    const float2* __restrict__ aux, const float* __restrict__ a_d,
    const float* __restrict__ b_gcn, const float* __restrict__ bl,
    const float* __restrict__ b_gat, const float* __restrict__ w,
    ushort_t* __restrict__ ensb) {
  int node = (blockIdx.x * blockDim.x + threadIdx.x) >> 6;
  int lane = threadIdx.x & 63;
  if (node >= NN) return;
  const int half = lane >> 5;  // 0/1
  const int fl = lane & 31;    // feature-pair index (feats 2fl, 2fl+1)
  int beg = offs[node];
  int c = cnt[node];
  int end = beg + c;
  float2 axd = aux[node];  // {dinv_d, a_s_d}
  float dd = axd.x;
  float a_dd = a_d[node];
  float ag0 = 0.f, ag1 = 0.f, as0 = 0.f, as1 = 0.f, aa0 = 0.f, aa1 = 0.f,
        dg = 0.f;
  int p = beg + half;
  for (; p + 2 < end; p += 4) {
    int sA = srcidx[p], sB = srcidx[p + 2];
    float2 axA = aux[sA], axB = aux[sB];
    const uint_t* hA = (const uint_t*)(Hb + (size_t)sA * 256);
    const uint_t* hB = (const uint_t*)(Hb + (size_t)sB * 256);
    uint_t gA = hA[fl], gB = hB[fl];
    uint_t qA = hA[32 + fl], qB = hB[32 + fl];
    uint_t tA = hA[64 + fl], tB = hB[64 + fl];
    float exA = __expf(leaky02(axA.y + a_dd));
    float exB = __expf(leaky02(axB.y + a_dd));
    float nA = axA.x * dd, nB = axB.x * dd;
    ag0 = fmaf(bflo(gA), nA, ag0); ag1 = fmaf(bfhi(gA), nA, ag1);
    ag0 = fmaf(bflo(gB), nB, ag0); ag1 = fmaf(bfhi(gB), nB, ag1);
    as0 += bflo(qA) + bflo(qB);    as1 += bfhi(qA) + bfhi(qB);
    aa0 = fmaf(bflo(tA), exA, aa0); aa1 = fmaf(bfhi(tA), exA, aa1);
    aa0 = fmaf(bflo(tB), exB, aa0); aa1 = fmaf(bfhi(tB), exB, aa1);
    dg += exA + exB;
  }
  if (p < end) {
    int sA = srcidx[p];
    float2 axA = aux[sA];
    const uint_t* hA = (const uint_t*)(Hb + (size_t)sA * 256);
    uint_t gA = hA[fl], qA = hA[32 + fl], tA = hA[64 + fl];
    float exA = __expf(leaky02(axA.y + a_dd));
    float nA = axA.x * dd;
    ag0 = fmaf(bflo(gA), nA, ag0); ag1 = fmaf(bfhi(gA), nA, ag1);
    as0 += bflo(qA);               as1 += bfhi(qA);
    aa0 = fmaf(bflo(tA), exA, aa0); aa1 = fmaf(bfhi(tA), exA, aa1);
    dg += exA;
  }
  // fold halves
  ag0 += __shfl_xor(ag0, 32, 64); ag1 += __shfl_xor(ag1, 32, 64);
  as0 += __shfl_xor(as0, 32, 64); as1 += __shfl_xor(as1, 32, 64);
  aa0 += __shfl_xor(aa0, 32, 64); aa1 += __shfl_xor(aa1, 32, 64);
  dg += __shfl_xor(dg, 32, 64);
  // epilogue (half 0 stores)
  const uint_t* hd = (const uint_t*)(Hb + (size_t)node * 256);
  uint_t hg = hd[fl], ht = hd[64 + fl], hr = hd[96 + fl];
  float2 bg = ((const float2*)b_gcn)[fl];
  float2 bs = ((const float2*)bl)[fl];
  float2 ba = ((const float2*)b_gat)[fl];
  float exl = __expf(leaky02(axd.y + a_dd));
  float dd2 = dd * dd;
  float cinv = 1.0f / fmaxf((float)c, 1.0f);
  float gdi = 1.0f / (dg + exl + 1e-16f);
  float g0 = ag0 + dd2 * bflo(hg) + bg.x;
  float g1 = ag1 + dd2 * bfhi(hg) + bg.y;
  float s0 = as0 * cinv + bs.x + bflo(hr);
  float s1 = as1 * cinv + bs.y + bfhi(hr);
  float t0 = (aa0 + exl * bflo(ht)) * gdi + ba.x;
  float t1 = (aa1 + exl * bfhi(ht)) * gdi + ba.y;
  float w0 = w[0], w1 = w[1], w2 = w[2];
  float e0 = w0 * gelu_exact(g0) + w1 * gelu_exact(s0) + w2 * gelu_exact(t0);
  float e1 = w0 * gelu_exact(g1) + w1 * gelu_exact(s1) + w2 * gelu_exact(t1);
  if (half == 0) ((uint_t*)ensb)[(size_t)node * 32 + fl] = f2bf2(e0, e1);
}

// ---------------- MFMA GEMM B: QKVSb = bf16(ens @ [Wq|Wk|Wv|Wskip] + bias) -----
__global__ __launch_bounds__(256) void k_gemmB(
    const ushort_t* __restrict__ ensb, const ushort_t* __restrict__ WtB,
    const float* __restrict__ bcat, ushort_t* __restrict__ QKVSb) {
  __shared__ __align__(16) ushort_t wb[160 * 72];  // [c][k] padded +8
  __shared__ float bsh[160];
  const int t = threadIdx.x;
  for (int idx = t; idx < 160 * 8; idx += 256) {
    int c = idx >> 3, ch = idx & 7;
    *(uint4*)&wb[c * 72 + ch * 8] = *(const uint4*)(WtB + c * 64 + ch * 8);
  }
  if (t < 160) bsh[t] = bcat[t];
  __syncthreads();
  const int wv = t >> 6, l = t & 63;
  const int lr = l & 15, lg = l >> 4;
  const int rbase = blockIdx.x * 64 + wv * 16;
  int arow = rbase + lr;
  int arowc = arow < NN ? arow : NN - 1;
  const ushort_t* ap = ensb + (size_t)arowc * 64 + lg * 8;
  f32x4 acc[10] = {};
#pragma unroll
  for (int ks = 0; ks < 2; ++ks) {
    s16x8 af = *(const s16x8*)(ap + ks * 32);
#pragma unroll
    for (int n = 0; n < 10; ++n) {
      s16x8 bf = *(const s16x8*)&wb[(n * 16 + lr) * 72 + ks * 32 + lg * 8];
      acc[n] = __builtin_amdgcn_mfma_f32_16x16x32_bf16(af, bf, acc[n], 0, 0, 0);
    }
  }
#pragma unroll
  for (int n = 0; n < 10; ++n) {
    int col = n * 16 + lr;
#pragma unroll
    for (int j = 0; j < 4; ++j) {
      int orow = rbase + lg * 4 + j;
      if (orow < NN)
        QKVSb[(size_t)orow * 160 + col] = f2bf(acc[n][j] + bsh[col]);
    }
  }
}

// ---------------- edge-parallel transformer scores (8 lanes/edge) --------------
__global__ __launch_bounds__(256) void k_score(
    const int* __restrict__ srcidx, const int* __restrict__ dsts,
    const ushort_t* __restrict__ QKVSb, float* __restrict__ escore) {
  int p = (blockIdx.x * 256 + threadIdx.x) >> 3;
  int l = threadIdx.x & 7;
  if (p >= EE) return;
  int s = srcidx[p], d = dsts[p];
  float part = 0.f;
  if (l < 5) {
    const uint4 qv = *(const uint4*)(QKVSb + (size_t)d * 160 + l * 8);
    const uint4 kv = *(const uint4*)(QKVSb + (size_t)s * 160 + 40 + l * 8);
    part = bflo(qv.x) * bflo(kv.x);
    part = fmaf(bfhi(qv.x), bfhi(kv.x), part);
    part = fmaf(bflo(qv.y), bflo(kv.y), part);
    part = fmaf(bfhi(qv.y), bfhi(kv.y), part);
    part = fmaf(bflo(qv.z), bflo(kv.z), part);
    part = fmaf(bfhi(qv.z), bfhi(kv.z), part);
    part = fmaf(bflo(qv.w), bflo(kv.w), part);
    part = fmaf(bfhi(qv.w), bfhi(kv.w), part);
  }
  part += __shfl_xor(part, 1, 64);
  part += __shfl_xor(part, 2, 64);
  part += __shfl_xor(part, 4, 64);
  if (l == 0) escore[p] = __expf(part * 0.15811388300841897f);
}

// ---------------- transformer aggregation + log_softmax ------------------------
// 1 node/wave; two 32-lane halves over alternating edges; packed uint v loads.
__global__ __launch_bounds__(256) void k_agg2(
    const int* __restrict__ srcidx, const int* __restrict__ offs,
    const int* __restrict__ cnt, const ushort_t* __restrict__ QKVSb,
    const float* __restrict__ escore, float* __restrict__ out) {
  int node = (blockIdx.x * blockDim.x + threadIdx.x) >> 6;
  int lane = threadIdx.x & 63;
  if (node >= NN) return;
  const int half = lane >> 5;
  const int fl = lane & 31;   // feature-pair index (feats 2fl, 2fl+1 of 40)
  const bool valid = fl < 20;
  int beg = offs[node];
  int end = beg + cnt[node];
  float den = 0.f, av0 = 0.f, av1 = 0.f;
  int p = beg + half;
  for (; p + 2 < end; p += 4) {
    int sA = srcidx[p], sB = srcidx[p + 2];
    float eA = escore[p], eB = escore[p + 2];
    uint_t vA = valid ? ((const uint_t*)(QKVSb + (size_t)sA * 160))[40 + fl] : 0u;
    uint_t vB = valid ? ((const uint_t*)(QKVSb + (size_t)sB * 160))[40 + fl] : 0u;
    av0 = fmaf(eA, bflo(vA), av0); av1 = fmaf(eA, bfhi(vA), av1);
    av0 = fmaf(eB, bflo(vB), av0); av1 = fmaf(eB, bfhi(vB), av1);
    den += eA + eB;
  }
  if (p < end) {
    int sA = srcidx[p];
    float eA = escore[p];
    uint_t vA = valid ? ((const uint_t*)(QKVSb + (size_t)sA * 160))[40 + fl] : 0u;
    av0 = fmaf(eA, bflo(vA), av0); av1 = fmaf(eA, bfhi(vA), av1);
    den += eA;
  }
  // fold halves
  av0 += __shfl_xor(av0, 32, 64);
  av1 += __shfl_xor(av1, 32, 64);
  den += __shfl_xor(den, 32, 64);
  const uint_t* rd = (const uint_t*)(QKVSb + (size_t)node * 160);
  uint_t sk = valid ? rd[60 + fl] : 0u;
  float di = 1.0f / (den + 1e-16f);
  float o0 = valid ? av0 * di + bflo(sk) : -3.0e38f;
  float o1 = valid ? av1 * di + bfhi(sk) : -3.0e38f;
  float m = half_max(fmaxf(o0, o1));
  float eo = valid ? __expf(o0 - m) + __expf(o1 - m) : 0.f;
  float ls = logf(half_sum(eo));
  if (valid && half == 0) {
    float2 r = make_float2(o0 - m - ls, o1 - m - ls);
    ((float2*)out)[(size_t)node * 20 + fl] = r;
  }
}

extern "C" void kernel_launch(void* const* d_in, const int* in_sizes, int n_in,
                              void* d_out, int out_size, void* d_ws,
                              size_t ws_size, hipStream_t stream) {
  const float* x     = (const float*)d_in[0];
  const int*   ei    = (const int*)d_in[1];
  const float* w     = (const float*)d_in[2];
  const float* W_gcn = (const float*)d_in[3];
  const float* b_gcn = (const float*)d_in[4];
  const float* Wl    = (const float*)d_in[5];
  const float* bl    = (const float*)d_in[6];
  const float* Wr    = (const float*)d_in[7];
  const float* W_gat = (const float*)d_in[8];
  const float* att_s = (const float*)d_in[9];
  const float* att_d = (const float*)d_in[10];
  const float* b_gat = (const float*)d_in[11];
  const float* Wq    = (const float*)d_in[12];
  const float* bq    = (const float*)d_in[13];
  const float* Wk    = (const float*)d_in[14];
  const float* bk    = (const float*)d_in[15];
  const float* Wv    = (const float*)d_in[16];
  const float* bv    = (const float*)d_in[17];
  const float* Wsk   = (const float*)d_in[18];
  const float* bsk   = (const float*)d_in[19];
  float* out = (float*)d_out;
  float* ws  = (float*)d_ws;

  const int* src = ei;
  const int* dst = ei + EE;

  // workspace layout (float-unit offsets)
  ushort_t* Hb     = (ushort_t*)ws;                       // 256N ush = 128N fl
  ushort_t* ensb   = (ushort_t*)(ws + (size_t)128 * NN);  // 64N ush = 32N fl
  float*    a_s    = ws + (size_t)160 * NN;               // N
  float*    a_d    = ws + (size_t)161 * NN;               // N
  float2*   aux    = (float2*)(ws + (size_t)162 * NN);    // 2N
  ushort_t* qkvsb  = (ushort_t*)(ws + (size_t)164 * NN);  // 160N ush = 80N fl
  ushort_t* xb     = (ushort_t*)(ws + (size_t)244 * NN);  // 128N ush = 64N fl
  ushort_t* WtA    = (ushort_t*)(ws + (size_t)308 * NN);  // 32768 ush
  ushort_t* WtB    = (ushort_t*)(ws + (size_t)308 * NN + 16384);  // 10240 ush
  float*    bcat   = ws + (size_t)308 * NN + 21504;       // 160 fl
  float*    escore = ws + (size_t)308 * NN + 21664;       // EE fl
  int*      ibase  = (int*)(ws + (size_t)308 * NN + 21664 + EE);
  int*      cnt    = ibase;                               // N
  int*      offs   = ibase + NN;                          // N
  int*      cursor = ibase + 2 * NN;                      // N
  int*      srcidx = ibase + 3 * NN;                      // EE
  int*      dsts   = ibase + 3 * NN + EE;                 // EE
  int*      bsum   = ibase + 3 * NN + 2 * EE;             // NBLK
  int*      boffs  = bsum + NBLK;                         // NBLK

  hipMemsetAsync(cnt, 0, (size_t)NN * sizeof(int), stream);

  k_castx<<<(NN * FIN / 4 + 255) / 256, 256, 0, stream>>>(x, xb);
  k_prepw<<<(43168 + 255) / 256, 256, 0, stream>>>(
      W_gcn, Wl, W_gat, Wr, Wq, Wk, Wv, Wsk, bq, bk, bv, bsk, WtA, WtB, bcat);

  dim3 gA((NN + 63) / 64, 4);
  k_gemmA<<<gA, 256, 0, stream>>>(xb, WtA, Hb);
  k_att<<<(NN + 3) / 4, 256, 0, stream>>>(Hb, att_s, att_d, a_s, a_d);
  k_hist<<<(EE + 255) / 256, 256, 0, stream>>>(dst, cnt);
  k_bsum<<<NBLK, SCB, 0, stream>>>(cnt, bsum);
  k_bscan<<<1, SCB, 0, stream>>>(bsum, boffs);
  k_apply<<<NBLK, SCB, 0, stream>>>(cnt, boffs, offs, cursor, a_s, aux);
  k_scatter<<<(EE + 255) / 256, 256, 0, stream>>>(src, dst, cursor, srcidx,
                                                  dsts);
  k_agg1<<<(NN + 3) / 4, 256, 0, stream>>>(srcidx, offs, cnt, Hb, aux, a_d,
                                           b_gcn, bl, b_gat, w, ensb);
  k_gemmB<<<(NN + 63) / 64, 256, 0, stream>>>(ensb, WtB, bcat, qkvsb);
  k_score<<<(EE * 8 + 255) / 256, 256, 0, stream>>>(srcidx, dsts, qkvsb,
                                                    escore);
  k_agg2<<<(NN + 3) / 4, 256, 0, stream>>>(srcidx, offs, cnt, qkvsb, escore,
                                           out);
}

// Round 8
// 225.814 us; speedup vs baseline: 4.1017x; 1.1053x over previous
//
#include <hip/hip_runtime.h>
#include <math.h>

#define NN 50000
#define EE 800000
#define FIN 128
#define HID 64
#define CL 40
#define SCB 256
#define NBLK ((NN + SCB - 1) / SCB)  // 196

typedef unsigned short ushort_t;
typedef unsigned int uint_t;
typedef float f32x4 __attribute__((ext_vector_type(4)));
typedef short s16x8 __attribute__((ext_vector_type(8)));

__device__ __forceinline__ ushort_t f2bf(float f) {
  uint_t u = __float_as_uint(f);
  u = (u + 0x7FFFu + ((u >> 16) & 1u)) >> 16;  // RNE
  return (ushort_t)u;
}
__device__ __forceinline__ uint_t f2bf2(float lo, float hi) {
  return (uint_t)f2bf(lo) | ((uint_t)f2bf(hi) << 16);
}
__device__ __forceinline__ float bf2f(ushort_t s) {
  return __uint_as_float(((uint_t)s) << 16);
}
__device__ __forceinline__ float bflo(uint_t u) {
  return __uint_as_float(u << 16);
}
__device__ __forceinline__ float bfhi(uint_t u) {
  return __uint_as_float(u & 0xFFFF0000u);
}

__device__ __forceinline__ int wave_sum_i(int v) {
#pragma unroll
  for (int off = 32; off > 0; off >>= 1) v += __shfl_xor(v, off, 64);
  return v;
}
__device__ __forceinline__ float half_sum(float v) {  // within 32-lane half
#pragma unroll
  for (int off = 16; off > 0; off >>= 1) v += __shfl_xor(v, off, 64);
  return v;
}
__device__ __forceinline__ float half_max(float v) {
#pragma unroll
  for (int off = 16; off > 0; off >>= 1) v = fmaxf(v, __shfl_xor(v, off, 64));
  return v;
}
__device__ __forceinline__ float gelu_exact(float x) {
  return 0.5f * x * (1.0f + erff(x * 0.70710678118654752f));
}
__device__ __forceinline__ float leaky02(float x) {
  return x >= 0.f ? x : 0.2f * x;
}

// ---------------- fused prep: castx (blocks<6250) | prepw | hist ---------------
#define PREP_CAST 6250   // NN*FIN/4 / 256
#define PREP_W 169       // ceil(43168/256)
#define PREP_HIST 3125   // EE/256
__global__ __launch_bounds__(256) void k_prep(
    const float* __restrict__ x, const int* __restrict__ dst,
    const float* __restrict__ W0, const float* __restrict__ W1,
    const float* __restrict__ W2, const float* __restrict__ W3,
    const float* __restrict__ Q0, const float* __restrict__ Q1,
    const float* __restrict__ Q2, const float* __restrict__ Q3,
    const float* __restrict__ b0, const float* __restrict__ b1,
    const float* __restrict__ b2, const float* __restrict__ b3,
    ushort_t* __restrict__ xb, ushort_t* __restrict__ WtA,
    ushort_t* __restrict__ WtB, float* __restrict__ bcat,
    int* __restrict__ cnt) {
  int b = blockIdx.x, t = threadIdx.x;
  if (b < PREP_CAST) {
    int i = b * 256 + t;
    if (i < NN * FIN / 4) {
      float4 v = ((const float4*)x)[i];
      ushort4 o;
      o.x = f2bf(v.x); o.y = f2bf(v.y); o.z = f2bf(v.z); o.w = f2bf(v.w);
      ((ushort4*)xb)[i] = o;
    }
  } else if (b < PREP_CAST + PREP_W) {
    int idx = (b - PREP_CAST) * 256 + t;
    if (idx < 32768) {
      int m = idx >> 13, r = idx & 8191, c = r >> 7, k = r & 127;
      const float* W = (m == 0) ? W0 : (m == 1) ? W1 : (m == 2) ? W2 : W3;
      WtA[idx] = f2bf(W[k * HID + c]);
    } else if (idx < 43008) {
      int j = idx - 32768;
      int c = j >> 6, k = j & 63;
      int mm = c / CL, cc = c % CL;
      const float* W = (mm == 0) ? Q0 : (mm == 1) ? Q1 : (mm == 2) ? Q2 : Q3;
      WtB[j] = f2bf(W[k * CL + cc]);
    } else if (idx < 43168) {
      int c = idx - 43008;
      int mm = c / CL, cc = c % CL;
      const float* bb = (mm == 0) ? b0 : (mm == 1) ? b1 : (mm == 2) ? b2 : b3;
      bcat[c] = bb[cc];
    }
  } else {
    int e = (b - PREP_CAST - PREP_W) * 256 + t;
    if (e < EE) atomicAdd(&cnt[dst[e]], 1);
  }
}

// ---------------- MFMA GEMM A (+fused att scalars on m==2) ---------------------
__global__ __launch_bounds__(256) void k_gemmA(
    const ushort_t* __restrict__ xb, const ushort_t* __restrict__ WtA,
    const float* __restrict__ attS, const float* __restrict__ attD,
    ushort_t* __restrict__ Hb, float* __restrict__ a_s,
    float* __restrict__ a_d) {
  __shared__ __align__(16) ushort_t wlds[64 * 136];  // [c][k] padded +8
  const int t = threadIdx.x;
  const int m = blockIdx.y;
  for (int idx = t; idx < 64 * 16; idx += 256) {
    int c = idx >> 4, ch = idx & 15;
    *(uint4*)&wlds[c * 136 + ch * 8] =
        *(const uint4*)(WtA + m * 8192 + c * 128 + ch * 8);
  }
  __syncthreads();
  const int wv = t >> 6, l = t & 63;
  const int lr = l & 15, lg = l >> 4;
  const int rbase = blockIdx.x * 64 + wv * 16;
  int arow = rbase + lr;
  int arowc = arow < NN ? arow : NN - 1;
  const ushort_t* ap = xb + (size_t)arowc * 128 + lg * 8;
  f32x4 acc[4] = {};
#pragma unroll
  for (int ks = 0; ks < 4; ++ks) {
    s16x8 af = *(const s16x8*)(ap + ks * 32);
#pragma unroll
    for (int n = 0; n < 4; ++n) {
      s16x8 bf = *(const s16x8*)&wlds[(n * 16 + lr) * 136 + ks * 32 + lg * 8];
      acc[n] = __builtin_amdgcn_mfma_f32_16x16x32_bf16(af, bf, acc[n], 0, 0, 0);
    }
  }
#pragma unroll
  for (int n = 0; n < 4; ++n) {
#pragma unroll
    for (int j = 0; j < 4; ++j) {
      int orow = rbase + lg * 4 + j;
      if (orow < NN)
        Hb[(size_t)orow * 256 + m * 64 + n * 16 + lr] = f2bf(acc[n][j]);
    }
  }
  if (m == 2) {  // GAT block: a_s/a_d from fp32 acc. col = n*16+lr, row=lg*4+j
    float sat[4], dat[4];
#pragma unroll
    for (int n = 0; n < 4; ++n) {
      sat[n] = attS[n * 16 + lr];
      dat[n] = attD[n * 16 + lr];
    }
#pragma unroll
    for (int j = 0; j < 4; ++j) {
      float ps = 0.f, pd = 0.f;
#pragma unroll
      for (int n = 0; n < 4; ++n) {
        ps = fmaf(acc[n][j], sat[n], ps);
        pd = fmaf(acc[n][j], dat[n], pd);
      }
#pragma unroll
      for (int off = 1; off < 16; off <<= 1) {
        ps += __shfl_xor(ps, off, 64);
        pd += __shfl_xor(pd, off, 64);
      }
      int orow = rbase + lg * 4 + j;
      if (lr == 0 && orow < NN) { a_s[orow] = ps; a_d[orow] = pd; }
    }
  }
}

// ---------------- block sums of cnt --------------------------------------------
__global__ __launch_bounds__(SCB) void k_bsum(const int* __restrict__ cnt,
                                              int* __restrict__ bsum) {
  __shared__ int wsm[4];
  int i = blockIdx.x * SCB + threadIdx.x;
  int v = (i < NN) ? cnt[i] : 0;
  int s = wave_sum_i(v);
  int lane = threadIdx.x & 63, wv = threadIdx.x >> 6;
  if (lane == 0) wsm[wv] = s;
  __syncthreads();
  if (threadIdx.x == 0) bsum[blockIdx.x] = wsm[0] + wsm[1] + wsm[2] + wsm[3];
}

// ---------------- fused bscan+apply: each block computes its own prefix --------
__global__ __launch_bounds__(SCB) void k_scanapply(
    const int* __restrict__ cnt, const int* __restrict__ bsum,
    int* __restrict__ offs, int* __restrict__ cursor,
    float* __restrict__ dinv) {
  __shared__ int ts[SCB];
  __shared__ int wred[4];
  int b = blockIdx.x, t = threadIdx.x;
  int pv = (t < b) ? bsum[t] : 0;  // b<=195, so t<b implies t<196=NBLK
  int ps = wave_sum_i(pv);
  int lane = t & 63, wv = t >> 6;
  if (lane == 0) wred[wv] = ps;
  int i = b * SCB + t;
  int v = (i < NN) ? cnt[i] : 0;
  ts[t] = v;
  __syncthreads();
  int prefix = wred[0] + wred[1] + wred[2] + wred[3];
  for (int off = 1; off < SCB; off <<= 1) {
    int u = (t >= off) ? ts[t - off] : 0;
    __syncthreads();
    ts[t] += u;
    __syncthreads();
  }
  if (i < NN) {
    int ex = ts[t] - v + prefix;
    offs[i] = ex;
    cursor[i] = ex;
    dinv[i] = rsqrtf((float)v + 1.0f);
  }
}

// ---------------- counting-sort scatter + per-edge scalar precompute -----------
__global__ __launch_bounds__(256) void k_scatter(
    const int* __restrict__ src, const int* __restrict__ dst,
    int* __restrict__ cursor, const float* __restrict__ a_s,
    const float* __restrict__ a_d, const float* __restrict__ dinv,
    int* __restrict__ srcidx, int* __restrict__ dsts,
    float2* __restrict__ edata) {
  int e = blockIdx.x * blockDim.x + threadIdx.x;
  if (e < EE) {
    int s = src[e], d = dst[e];
    int p = atomicAdd(&cursor[d], 1);
    srcidx[p] = s;
    dsts[p] = d;
    float ex = __expf(leaky02(a_s[s] + a_d[d]));
    edata[p] = make_float2(dinv[s] * dinv[d], ex);
  }
}

// ---------------- fused GCN+SAGE+GAT aggregation + gelu ensemble ---------------
// 1 node/wave; two 32-lane halves; 4 edges/half in flight; packed uint loads.
__global__ __launch_bounds__(256) void k_agg1(
    const int* __restrict__ srcidx, const int* __restrict__ offs,
    const int* __restrict__ cnt, const ushort_t* __restrict__ Hb,
    const float2* __restrict__ edata, const float* __restrict__ dinv,
    const float* __restrict__ a_s, const float* __restrict__ a_d,
    const float* __restrict__ b_gcn, const float* __restrict__ bl,
    const float* __restrict__ b_gat, const float* __restrict__ w,
    ushort_t* __restrict__ ensb) {
  int node = (blockIdx.x * blockDim.x + threadIdx.x) >> 6;
  int lane = threadIdx.x & 63;
  if (node >= NN) return;
  const int half = lane >> 5;
  const int fl = lane & 31;
  int beg = offs[node];
  int c = cnt[node];
  int end = beg + c;
  float ag0 = 0.f, ag1 = 0.f, as0 = 0.f, as1 = 0.f, aa0 = 0.f, aa1 = 0.f,
        dg = 0.f;
  int p = beg + half;
  for (; p + 6 < end; p += 8) {
    int sA = srcidx[p], sB = srcidx[p + 2], sC = srcidx[p + 4],
        sD = srcidx[p + 6];
    float2 eA = edata[p], eB = edata[p + 2], eC = edata[p + 4],
           eD = edata[p + 6];
    const uint_t* hA = (const uint_t*)(Hb + (size_t)sA * 256);
    const uint_t* hB = (const uint_t*)(Hb + (size_t)sB * 256);
    const uint_t* hC = (const uint_t*)(Hb + (size_t)sC * 256);
    const uint_t* hD = (const uint_t*)(Hb + (size_t)sD * 256);
    uint_t gA = hA[fl], qA = hA[32 + fl], tA = hA[64 + fl];
    uint_t gB = hB[fl], qB = hB[32 + fl], tB = hB[64 + fl];
    uint_t gC = hC[fl], qC = hC[32 + fl], tC = hC[64 + fl];
    uint_t gD = hD[fl], qD = hD[32 + fl], tD = hD[64 + fl];
    ag0 = fmaf(bflo(gA), eA.x, ag0); ag1 = fmaf(bfhi(gA), eA.x, ag1);
    ag0 = fmaf(bflo(gB), eB.x, ag0); ag1 = fmaf(bfhi(gB), eB.x, ag1);
    ag0 = fmaf(bflo(gC), eC.x, ag0); ag1 = fmaf(bfhi(gC), eC.x, ag1);
    ag0 = fmaf(bflo(gD), eD.x, ag0); ag1 = fmaf(bfhi(gD), eD.x, ag1);
    as0 += (bflo(qA) + bflo(qB)) + (bflo(qC) + bflo(qD));
    as1 += (bfhi(qA) + bfhi(qB)) + (bfhi(qC) + bfhi(qD));
    aa0 = fmaf(bflo(tA), eA.y, aa0); aa1 = fmaf(bfhi(tA), eA.y, aa1);
    aa0 = fmaf(bflo(tB), eB.y, aa0); aa1 = fmaf(bfhi(tB), eB.y, aa1);
    aa0 = fmaf(bflo(tC), eC.y, aa0); aa1 = fmaf(bfhi(tC), eC.y, aa1);
    aa0 = fmaf(bflo(tD), eD.y, aa0); aa1 = fmaf(bfhi(tD), eD.y, aa1);
    dg += (eA.y + eB.y) + (eC.y + eD.y);
  }
  for (; p < end; p += 2) {
    int sA = srcidx[p];
    float2 eA = edata[p];
    const uint_t* hA = (const uint_t*)(Hb + (size_t)sA * 256);
    uint_t gA = hA[fl], qA = hA[32 + fl], tA = hA[64 + fl];
    ag0 = fmaf(bflo(gA), eA.x, ag0); ag1 = fmaf(bfhi(gA), eA.x, ag1);
    as0 += bflo(qA);                 as1 += bfhi(qA);
    aa0 = fmaf(bflo(tA), eA.y, aa0); aa1 = fmaf(bfhi(tA), eA.y, aa1);
    dg += eA.y;
  }
  // fold halves
  ag0 += __shfl_xor(ag0, 32, 64); ag1 += __shfl_xor(ag1, 32, 64);
  as0 += __shfl_xor(as0, 32, 64); as1 += __shfl_xor(as1, 32, 64);
  aa0 += __shfl_xor(aa0, 32, 64); aa1 += __shfl_xor(aa1, 32, 64);
  dg += __shfl_xor(dg, 32, 64);
  // epilogue
  float dd = dinv[node];
  float exl = __expf(leaky02(a_s[node] + a_d[node]));
  const uint_t* hd = (const uint_t*)(Hb + (size_t)node * 256);
  uint_t hg = hd[fl], ht = hd[64 + fl], hr = hd[96 + fl];
  float2 bg = ((const float2*)b_gcn)[fl];
  float2 bs = ((const float2*)bl)[fl];
  float2 ba = ((const float2*)b_gat)[fl];
  float dd2 = dd * dd;
  float cinv = 1.0f / fmaxf((float)c, 1.0f);
  float gdi = 1.0f / (dg + exl + 1e-16f);
  float g0 = ag0 + dd2 * bflo(hg) + bg.x;
  float g1 = ag1 + dd2 * bfhi(hg) + bg.y;
  float s0 = as0 * cinv + bs.x + bflo(hr);
  float s1 = as1 * cinv + bs.y + bfhi(hr);
  float t0 = (aa0 + exl * bflo(ht)) * gdi + ba.x;
  float t1 = (aa1 + exl * bfhi(ht)) * gdi + ba.y;
  float w0 = w[0], w1 = w[1], w2 = w[2];
  float e0 = w0 * gelu_exact(g0) + w1 * gelu_exact(s0) + w2 * gelu_exact(t0);
  float e1 = w0 * gelu_exact(g1) + w1 * gelu_exact(s1) + w2 * gelu_exact(t1);
  if (half == 0) ((uint_t*)ensb)[(size_t)node * 32 + fl] = f2bf2(e0, e1);
}

// ---------------- MFMA GEMM B: QKVSb = bf16(ens @ [Wq|Wk|Wv|Wskip] + bias) -----
__global__ __launch_bounds__(256) void k_gemmB(
    const ushort_t* __restrict__ ensb, const ushort_t* __restrict__ WtB,
    const float* __restrict__ bcat, ushort_t* __restrict__ QKVSb) {
  __shared__ __align__(16) ushort_t wb[160 * 72];  // [c][k] padded +8
  __shared__ float bsh[160];
  const int t = threadIdx.x;
  for (int idx = t; idx < 160 * 8; idx += 256) {
    int c = idx >> 3, ch = idx & 7;
    *(uint4*)&wb[c * 72 + ch * 8] = *(const uint4*)(WtB + c * 64 + ch * 8);
  }
  if (t < 160) bsh[t] = bcat[t];
  __syncthreads();
  const int wv = t >> 6, l = t & 63;
  const int lr = l & 15, lg = l >> 4;
  const int rbase = blockIdx.x * 64 + wv * 16;
  int arow = rbase + lr;
  int arowc = arow < NN ? arow : NN - 1;
  const ushort_t* ap = ensb + (size_t)arowc * 64 + lg * 8;
  f32x4 acc[10] = {};
#pragma unroll
  for (int ks = 0; ks < 2; ++ks) {
    s16x8 af = *(const s16x8*)(ap + ks * 32);
#pragma unroll
    for (int n = 0; n < 10; ++n) {
      s16x8 bf = *(const s16x8*)&wb[(n * 16 + lr) * 72 + ks * 32 + lg * 8];
      acc[n] = __builtin_amdgcn_mfma_f32_16x16x32_bf16(af, bf, acc[n], 0, 0, 0);
    }
  }
#pragma unroll
  for (int n = 0; n < 10; ++n) {
    int col = n * 16 + lr;
#pragma unroll
    for (int j = 0; j < 4; ++j) {
      int orow = rbase + lg * 4 + j;
      if (orow < NN)
        QKVSb[(size_t)orow * 160 + col] = f2bf(acc[n][j] + bsh[col]);
    }
  }
}

// ---------------- edge-parallel transformer scores (8 lanes/edge) --------------
__global__ __launch_bounds__(256) void k_score(
    const int* __restrict__ srcidx, const int* __restrict__ dsts,
    const ushort_t* __restrict__ QKVSb, float* __restrict__ escore) {
  int p = (blockIdx.x * 256 + threadIdx.x) >> 3;
  int l = threadIdx.x & 7;
  if (p >= EE) return;
  int s = srcidx[p], d = dsts[p];
  float part = 0.f;
  if (l < 5) {
    const uint4 qv = *(const uint4*)(QKVSb + (size_t)d * 160 + l * 8);
    const uint4 kv = *(const uint4*)(QKVSb + (size_t)s * 160 + 40 + l * 8);
    part = bflo(qv.x) * bflo(kv.x);
    part = fmaf(bfhi(qv.x), bfhi(kv.x), part);
    part = fmaf(bflo(qv.y), bflo(kv.y), part);
    part = fmaf(bfhi(qv.y), bfhi(kv.y), part);
    part = fmaf(bflo(qv.z), bflo(kv.z), part);
    part = fmaf(bfhi(qv.z), bfhi(kv.z), part);
    part = fmaf(bflo(qv.w), bflo(kv.w), part);
    part = fmaf(bfhi(qv.w), bfhi(kv.w), part);
  }
  part += __shfl_xor(part, 1, 64);
  part += __shfl_xor(part, 2, 64);
  part += __shfl_xor(part, 4, 64);
  if (l == 0) escore[p] = __expf(part * 0.15811388300841897f);
}

// ---------------- transformer aggregation + log_softmax ------------------------
__global__ __launch_bounds__(256) void k_agg2(
    const int* __restrict__ srcidx, const int* __restrict__ offs,
    const int* __restrict__ cnt, const ushort_t* __restrict__ QKVSb,
    const float* __restrict__ escore, float* __restrict__ out) {
  int node = (blockIdx.x * blockDim.x + threadIdx.x) >> 6;
  int lane = threadIdx.x & 63;
  if (node >= NN) return;
  const int half = lane >> 5;
  const int fl = lane & 31;   // feature-pair index (feats 2fl, 2fl+1 of 40)
  const bool valid = fl < 20;
  int beg = offs[node];
  int end = beg + cnt[node];
  float den = 0.f, av0 = 0.f, av1 = 0.f;
  int p = beg + half;
  for (; p + 6 < end; p += 8) {
    int sA = srcidx[p], sB = srcidx[p + 2], sC = srcidx[p + 4],
        sD = srcidx[p + 6];
    float eA = escore[p], eB = escore[p + 2], eC = escore[p + 4],
          eD = escore[p + 6];
    uint_t vA = valid ? ((const uint_t*)(QKVSb + (size_t)sA * 160))[40 + fl] : 0u;
    uint_t vB = valid ? ((const uint_t*)(QKVSb + (size_t)sB * 160))[40 + fl] : 0u;
    uint_t vC = valid ? ((const uint_t*)(QKVSb + (size_t)sC * 160))[40 + fl] : 0u;
    uint_t vD = valid ? ((const uint_t*)(QKVSb + (size_t)sD * 160))[40 + fl] : 0u;
    av0 = fmaf(eA, bflo(vA), av0); av1 = fmaf(eA, bfhi(vA), av1);
    av0 = fmaf(eB, bflo(vB), av0); av1 = fmaf(eB, bfhi(vB), av1);
    av0 = fmaf(eC, bflo(vC), av0); av1 = fmaf(eC, bfhi(vC), av1);
    av0 = fmaf(eD, bflo(vD), av0); av1 = fmaf(eD, bfhi(vD), av1);
    den += (eA + eB) + (eC + eD);
  }
  for (; p < end; p += 2) {
    int sA = srcidx[p];
    float eA = escore[p];
    uint_t vA = valid ? ((const uint_t*)(QKVSb + (size_t)sA * 160))[40 + fl] : 0u;
    av0 = fmaf(eA, bflo(vA), av0); av1 = fmaf(eA, bfhi(vA), av1);
    den += eA;
  }
  // fold halves
  av0 += __shfl_xor(av0, 32, 64);
  av1 += __shfl_xor(av1, 32, 64);
  den += __shfl_xor(den, 32, 64);
  const uint_t* rd = (const uint_t*)(QKVSb + (size_t)node * 160);
  uint_t sk = valid ? rd[60 + fl] : 0u;
  float di = 1.0f / (den + 1e-16f);
  float o0 = valid ? av0 * di + bflo(sk) : -3.0e38f;
  float o1 = valid ? av1 * di + bfhi(sk) : -3.0e38f;
  float m = half_max(fmaxf(o0, o1));
  float eo = valid ? __expf(o0 - m) + __expf(o1 - m) : 0.f;
  float ls = logf(half_sum(eo));
  if (valid && half == 0) {
    float2 r = make_float2(o0 - m - ls, o1 - m - ls);
    ((float2*)out)[(size_t)node * 20 + fl] = r;
  }
}

extern "C" void kernel_launch(void* const* d_in, const int* in_sizes, int n_in,
                              void* d_out, int out_size, void* d_ws,
                              size_t ws_size, hipStream_t stream) {
  const float* x     = (const float*)d_in[0];
  const int*   ei    = (const int*)d_in[1];
  const float* w     = (const float*)d_in[2];
  const float* W_gcn = (const float*)d_in[3];
  const float* b_gcn = (const float*)d_in[4];
  const float* Wl    = (const float*)d_in[5];
  const float* bl    = (const float*)d_in[6];
  const float* Wr    = (const float*)d_in[7];
  const float* W_gat = (const float*)d_in[8];
  const float* att_s = (const float*)d_in[9];
  const float* att_d = (const float*)d_in[10];
  const float* b_gat = (const float*)d_in[11];
  const float* Wq    = (const float*)d_in[12];
  const float* bq    = (const float*)d_in[13];
  const float* Wk    = (const float*)d_in[14];
  const float* bk    = (const float*)d_in[15];
  const float* Wv    = (const float*)d_in[16];
  const float* bv    = (const float*)d_in[17];
  const float* Wsk   = (const float*)d_in[18];
  const float* bsk   = (const float*)d_in[19];
  float* out = (float*)d_out;
  float* ws  = (float*)d_ws;

  const int* src = ei;
  const int* dst = ei + EE;

  // workspace layout (float-unit offsets)
  ushort_t* Hb     = (ushort_t*)ws;                       // 128N fl
  ushort_t* ensb   = (ushort_t*)(ws + (size_t)128 * NN);  // 32N fl
  float*    a_s    = ws + (size_t)160 * NN;               // N
  float*    a_d    = ws + (size_t)161 * NN;               // N
  float*    dinv   = ws + (size_t)162 * NN;               // N
  ushort_t* qkvsb  = (ushort_t*)(ws + (size_t)163 * NN);  // 80N fl
  ushort_t* xb     = (ushort_t*)(ws + (size_t)243 * NN);  // 64N fl
  ushort_t* WtA    = (ushort_t*)(ws + (size_t)307 * NN);  // 16384 fl
  ushort_t* WtB    = (ushort_t*)(ws + (size_t)307 * NN + 16384);  // 5120 fl
  float*    bcat   = ws + (size_t)307 * NN + 21504;       // 160 fl
  float*    escore = ws + (size_t)307 * NN + 21664;       // EE fl
  float2*   edata  = (float2*)(ws + (size_t)307 * NN + 21664 + EE);  // 2EE fl
  int*      ibase  = (int*)(ws + (size_t)307 * NN + 21664 + 3 * (size_t)EE);
  int*      cnt    = ibase;                               // N
  int*      offs   = ibase + NN;                          // N
  int*      cursor = ibase + 2 * NN;                      // N
  int*      srcidx = ibase + 3 * NN;                      // EE
  int*      dsts   = ibase + 3 * NN + EE;                 // EE
  int*      bsum   = ibase + 3 * NN + 2 * EE;             // NBLK

  hipMemsetAsync(cnt, 0, (size_t)NN * sizeof(int), stream);

  k_prep<<<PREP_CAST + PREP_W + PREP_HIST, 256, 0, stream>>>(
      x, dst, W_gcn, Wl, W_gat, Wr, Wq, Wk, Wv, Wsk, bq, bk, bv, bsk, xb, WtA,
      WtB, bcat, cnt);

  dim3 gA((NN + 63) / 64, 4);
  k_gemmA<<<gA, 256, 0, stream>>>(xb, WtA, att_s, att_d, Hb, a_s, a_d);
  k_bsum<<<NBLK, SCB, 0, stream>>>(cnt, bsum);
  k_scanapply<<<NBLK, SCB, 0, stream>>>(cnt, bsum, offs, cursor, dinv);
  k_scatter<<<(EE + 255) / 256, 256, 0, stream>>>(src, dst, cursor, a_s, a_d,
                                                  dinv, srcidx, dsts, edata);
  k_agg1<<<(NN + 3) / 4, 256, 0, stream>>>(srcidx, offs, cnt, Hb, edata, dinv,
                                           a_s, a_d, b_gcn, bl, b_gat, w, ensb);
  k_gemmB<<<(NN + 63) / 64, 256, 0, stream>>>(ensb, WtB, bcat, qkvsb);
  k_score<<<(EE * 8 + 255) / 256, 256, 0, stream>>>(srcidx, dsts, qkvsb,
                                                    escore);
  k_agg2<<<(NN + 3) / 4, 256, 0, stream>>>(srcidx, offs, cnt, qkvsb, escore,
                                           out);
}

// Round 9
// 219.121 us; speedup vs baseline: 4.2270x; 1.0305x over previous
//
#include <hip/hip_runtime.h>
#include <math.h>

#define NN 50000
#define EE 800000
#define FIN 128
#define HID 64
#define CL 40
#define SCB 256
#define NBLK ((NN + SCB - 1) / SCB)  // 196

typedef unsigned short ushort_t;
typedef unsigned int uint_t;
typedef float f32x4 __attribute__((ext_vector_type(4)));
typedef short s16x8 __attribute__((ext_vector_type(8)));

__device__ __forceinline__ ushort_t f2bf(float f) {
  uint_t u = __float_as_uint(f);
  u = (u + 0x7FFFu + ((u >> 16) & 1u)) >> 16;  // RNE
  return (ushort_t)u;
}
__device__ __forceinline__ uint_t f2bf2(float lo, float hi) {
  return (uint_t)f2bf(lo) | ((uint_t)f2bf(hi) << 16);
}
__device__ __forceinline__ float bf2f(ushort_t s) {
  return __uint_as_float(((uint_t)s) << 16);
}
__device__ __forceinline__ float bflo(uint_t u) {
  return __uint_as_float(u << 16);
}
__device__ __forceinline__ float bfhi(uint_t u) {
  return __uint_as_float(u & 0xFFFF0000u);
}

__device__ __forceinline__ int wave_sum_i(int v) {
#pragma unroll
  for (int off = 32; off > 0; off >>= 1) v += __shfl_xor(v, off, 64);
  return v;
}
__device__ __forceinline__ float half_sum(float v) {  // within 32-lane half
#pragma unroll
  for (int off = 16; off > 0; off >>= 1) v += __shfl_xor(v, off, 64);
  return v;
}
__device__ __forceinline__ float half_max(float v) {
#pragma unroll
  for (int off = 16; off > 0; off >>= 1) v = fmaxf(v, __shfl_xor(v, off, 64));
  return v;
}
__device__ __forceinline__ float gelu_exact(float x) {
  return 0.5f * x * (1.0f + erff(x * 0.70710678118654752f));
}
__device__ __forceinline__ float leaky02(float x) {
  return x >= 0.f ? x : 0.2f * x;
}

// ---------------- fused prep: castx | prepw | hist(+rank) ----------------------
#define PREP_CAST 6250   // NN*FIN/4 / 256
#define PREP_W 169       // ceil(43168/256)
#define PREP_HIST 3125   // EE/256
__global__ __launch_bounds__(256) void k_prep(
    const float* __restrict__ x, const int* __restrict__ dst,
    const float* __restrict__ W0, const float* __restrict__ W1,
    const float* __restrict__ W2, const float* __restrict__ W3,
    const float* __restrict__ Q0, const float* __restrict__ Q1,
    const float* __restrict__ Q2, const float* __restrict__ Q3,
    const float* __restrict__ b0, const float* __restrict__ b1,
    const float* __restrict__ b2, const float* __restrict__ b3,
    ushort_t* __restrict__ xb, ushort_t* __restrict__ WtA,
    ushort_t* __restrict__ WtB, float* __restrict__ bcat,
    int* __restrict__ cnt, int* __restrict__ erank) {
  int b = blockIdx.x, t = threadIdx.x;
  if (b < PREP_CAST) {
    int i = b * 256 + t;
    if (i < NN * FIN / 4) {
      float4 v = ((const float4*)x)[i];
      ushort4 o;
      o.x = f2bf(v.x); o.y = f2bf(v.y); o.z = f2bf(v.z); o.w = f2bf(v.w);
      ((ushort4*)xb)[i] = o;
    }
  } else if (b < PREP_CAST + PREP_W) {
    int idx = (b - PREP_CAST) * 256 + t;
    if (idx < 32768) {
      int m = idx >> 13, r = idx & 8191, c = r >> 7, k = r & 127;
      const float* W = (m == 0) ? W0 : (m == 1) ? W1 : (m == 2) ? W2 : W3;
      WtA[idx] = f2bf(W[k * HID + c]);
    } else if (idx < 43008) {
      int j = idx - 32768;
      int c = j >> 6, k = j & 63;
      int mm = c / CL, cc = c % CL;
      const float* W = (mm == 0) ? Q0 : (mm == 1) ? Q1 : (mm == 2) ? Q2 : Q3;
      WtB[j] = f2bf(W[k * CL + cc]);
    } else if (idx < 43168) {
      int c = idx - 43008;
      int mm = c / CL, cc = c % CL;
      const float* bb = (mm == 0) ? b0 : (mm == 1) ? b1 : (mm == 2) ? b2 : b3;
      bcat[c] = bb[cc];
    }
  } else {
    int e = (b - PREP_CAST - PREP_W) * 256 + t;
    if (e < EE) erank[e] = atomicAdd(&cnt[dst[e]], 1);
  }
}

// ---------------- MFMA GEMM A (+fused att scalars on m==2) ---------------------
__global__ __launch_bounds__(256) void k_gemmA(
    const ushort_t* __restrict__ xb, const ushort_t* __restrict__ WtA,
    const float* __restrict__ attS, const float* __restrict__ attD,
    ushort_t* __restrict__ Hb, float* __restrict__ a_s,
    float* __restrict__ a_d) {
  __shared__ __align__(16) ushort_t wlds[64 * 136];  // [c][k] padded +8
  const int t = threadIdx.x;
  const int m = blockIdx.y;
  for (int idx = t; idx < 64 * 16; idx += 256) {
    int c = idx >> 4, ch = idx & 15;
    *(uint4*)&wlds[c * 136 + ch * 8] =
        *(const uint4*)(WtA + m * 8192 + c * 128 + ch * 8);
  }
  __syncthreads();
  const int wv = t >> 6, l = t & 63;
  const int lr = l & 15, lg = l >> 4;
  const int rbase = blockIdx.x * 64 + wv * 16;
  int arow = rbase + lr;
  int arowc = arow < NN ? arow : NN - 1;
  const ushort_t* ap = xb + (size_t)arowc * 128 + lg * 8;
  f32x4 acc[4] = {};
#pragma unroll
  for (int ks = 0; ks < 4; ++ks) {
    s16x8 af = *(const s16x8*)(ap + ks * 32);
#pragma unroll
    for (int n = 0; n < 4; ++n) {
      s16x8 bf = *(const s16x8*)&wlds[(n * 16 + lr) * 136 + ks * 32 + lg * 8];
      acc[n] = __builtin_amdgcn_mfma_f32_16x16x32_bf16(af, bf, acc[n], 0, 0, 0);
    }
  }
#pragma unroll
  for (int n = 0; n < 4; ++n) {
#pragma unroll
    for (int j = 0; j < 4; ++j) {
      int orow = rbase + lg * 4 + j;
      if (orow < NN)
        Hb[(size_t)orow * 256 + m * 64 + n * 16 + lr] = f2bf(acc[n][j]);
    }
  }
  if (m == 2) {  // GAT block: a_s/a_d from fp32 acc. col = n*16+lr, row=lg*4+j
    float sat[4], dat[4];
#pragma unroll
    for (int n = 0; n < 4; ++n) {
      sat[n] = attS[n * 16 + lr];
      dat[n] = attD[n * 16 + lr];
    }
#pragma unroll
    for (int j = 0; j < 4; ++j) {
      float ps = 0.f, pd = 0.f;
#pragma unroll
      for (int n = 0; n < 4; ++n) {
        ps = fmaf(acc[n][j], sat[n], ps);
        pd = fmaf(acc[n][j], dat[n], pd);
      }
#pragma unroll
      for (int off = 1; off < 16; off <<= 1) {
        ps += __shfl_xor(ps, off, 64);
        pd += __shfl_xor(pd, off, 64);
      }
      int orow = rbase + lg * 4 + j;
      if (lr == 0 && orow < NN) { a_s[orow] = ps; a_d[orow] = pd; }
    }
  }
}

// ---------------- block sums of cnt --------------------------------------------
__global__ __launch_bounds__(SCB) void k_bsum(const int* __restrict__ cnt,
                                              int* __restrict__ bsum) {
  __shared__ int wsm[4];
  int i = blockIdx.x * SCB + threadIdx.x;
  int v = (i < NN) ? cnt[i] : 0;
  int s = wave_sum_i(v);
  int lane = threadIdx.x & 63, wv = threadIdx.x >> 6;
  if (lane == 0) wsm[wv] = s;
  __syncthreads();
  if (threadIdx.x == 0) bsum[blockIdx.x] = wsm[0] + wsm[1] + wsm[2] + wsm[3];
}

// ---------------- fused bscan+apply: each block computes its own prefix --------
__global__ __launch_bounds__(SCB) void k_scanapply(
    const int* __restrict__ cnt, const int* __restrict__ bsum,
    int* __restrict__ offs, float* __restrict__ dinv) {
  __shared__ int ts[SCB];
  __shared__ int wred[4];
  int b = blockIdx.x, t = threadIdx.x;
  int pv = (t < b) ? bsum[t] : 0;  // b<=195, so t<b implies t<196=NBLK
  int ps = wave_sum_i(pv);
  int lane = t & 63, wv = t >> 6;
  if (lane == 0) wred[wv] = ps;
  int i = b * SCB + t;
  int v = (i < NN) ? cnt[i] : 0;
  ts[t] = v;
  __syncthreads();
  int prefix = wred[0] + wred[1] + wred[2] + wred[3];
  for (int off = 1; off < SCB; off <<= 1) {
    int u = (t >= off) ? ts[t - off] : 0;
    __syncthreads();
    ts[t] += u;
    __syncthreads();
  }
  if (i < NN) {
    offs[i] = ts[t] - v + prefix;
    dinv[i] = rsqrtf((float)v + 1.0f);
  }
}

// ---------------- atomic-free scatter + per-edge scalar precompute -------------
__global__ __launch_bounds__(256) void k_scatter(
    const int* __restrict__ src, const int* __restrict__ dst,
    const int* __restrict__ erank, const int* __restrict__ offs,
    const float* __restrict__ a_s, const float* __restrict__ a_d,
    const float* __restrict__ dinv, int* __restrict__ srcidx,
    int* __restrict__ dsts, float2* __restrict__ edata) {
  int e = blockIdx.x * blockDim.x + threadIdx.x;
  if (e < EE) {
    int s = src[e], d = dst[e];
    int p = offs[d] + erank[e];
    srcidx[p] = s;
    dsts[p] = d;
    float ex = __expf(leaky02(a_s[s] + a_d[d]));
    edata[p] = make_float2(dinv[s] * dinv[d], ex);
  }
}

// ---------------- fused GCN+SAGE+GAT aggregation + gelu ensemble ---------------
// 1 node/wave; two 32-lane halves; 4 edges/half in flight; packed uint loads.
__global__ __launch_bounds__(256) void k_agg1(
    const int* __restrict__ srcidx, const int* __restrict__ offs,
    const int* __restrict__ cnt, const ushort_t* __restrict__ Hb,
    const float2* __restrict__ edata, const float* __restrict__ dinv,
    const float* __restrict__ a_s, const float* __restrict__ a_d,
    const float* __restrict__ b_gcn, const float* __restrict__ bl,
    const float* __restrict__ b_gat, const float* __restrict__ w,
    ushort_t* __restrict__ ensb) {
  int node = (blockIdx.x * blockDim.x + threadIdx.x) >> 6;
  int lane = threadIdx.x & 63;
  if (node >= NN) return;
  const int half = lane >> 5;
  const int fl = lane & 31;
  int beg = offs[node];
  int c = cnt[node];
  int end = beg + c;
  float ag0 = 0.f, ag1 = 0.f, as0 = 0.f, as1 = 0.f, aa0 = 0.f, aa1 = 0.f,
        dg = 0.f;
  int p = beg + half;
  for (; p + 6 < end; p += 8) {
    int sA = srcidx[p], sB = srcidx[p + 2], sC = srcidx[p + 4],
        sD = srcidx[p + 6];
    float2 eA = edata[p], eB = edata[p + 2], eC = edata[p + 4],
           eD = edata[p + 6];
    const uint_t* hA = (const uint_t*)(Hb + (size_t)sA * 256);
    const uint_t* hB = (const uint_t*)(Hb + (size_t)sB * 256);
    const uint_t* hC = (const uint_t*)(Hb + (size_t)sC * 256);
    const uint_t* hD = (const uint_t*)(Hb + (size_t)sD * 256);
    uint_t gA = hA[fl], qA = hA[32 + fl], tA = hA[64 + fl];
    uint_t gB = hB[fl], qB = hB[32 + fl], tB = hB[64 + fl];
    uint_t gC = hC[fl], qC = hC[32 + fl], tC = hC[64 + fl];
    uint_t gD = hD[fl], qD = hD[32 + fl], tD = hD[64 + fl];
    ag0 = fmaf(bflo(gA), eA.x, ag0); ag1 = fmaf(bfhi(gA), eA.x, ag1);
    ag0 = fmaf(bflo(gB), eB.x, ag0); ag1 = fmaf(bfhi(gB), eB.x, ag1);
    ag0 = fmaf(bflo(gC), eC.x, ag0); ag1 = fmaf(bfhi(gC), eC.x, ag1);
    ag0 = fmaf(bflo(gD), eD.x, ag0); ag1 = fmaf(bfhi(gD), eD.x, ag1);
    as0 += (bflo(qA) + bflo(qB)) + (bflo(qC) + bflo(qD));
    as1 += (bfhi(qA) + bfhi(qB)) + (bfhi(qC) + bfhi(qD));
    aa0 = fmaf(bflo(tA), eA.y, aa0); aa1 = fmaf(bfhi(tA), eA.y, aa1);
    aa0 = fmaf(bflo(tB), eB.y, aa0); aa1 = fmaf(bfhi(tB), eB.y, aa1);
    aa0 = fmaf(bflo(tC), eC.y, aa0); aa1 = fmaf(bfhi(tC), eC.y, aa1);
    aa0 = fmaf(bflo(tD), eD.y, aa0); aa1 = fmaf(bfhi(tD), eD.y, aa1);
    dg += (eA.y + eB.y) + (eC.y + eD.y);
  }
  for (; p < end; p += 2) {
    int sA = srcidx[p];
    float2 eA = edata[p];
    const uint_t* hA = (const uint_t*)(Hb + (size_t)sA * 256);
    uint_t gA = hA[fl], qA = hA[32 + fl], tA = hA[64 + fl];
    ag0 = fmaf(bflo(gA), eA.x, ag0); ag1 = fmaf(bfhi(gA), eA.x, ag1);
    as0 += bflo(qA);                 as1 += bfhi(qA);
    aa0 = fmaf(bflo(tA), eA.y, aa0); aa1 = fmaf(bfhi(tA), eA.y, aa1);
    dg += eA.y;
  }
  // fold halves
  ag0 += __shfl_xor(ag0, 32, 64); ag1 += __shfl_xor(ag1, 32, 64);
  as0 += __shfl_xor(as0, 32, 64); as1 += __shfl_xor(as1, 32, 64);
  aa0 += __shfl_xor(aa0, 32, 64); aa1 += __shfl_xor(aa1, 32, 64);
  dg += __shfl_xor(dg, 32, 64);
  // epilogue
  float dd = dinv[node];
  float exl = __expf(leaky02(a_s[node] + a_d[node]));
  const uint_t* hd = (const uint_t*)(Hb + (size_t)node * 256);
  uint_t hg = hd[fl], ht = hd[64 + fl], hr = hd[96 + fl];
  float2 bg = ((const float2*)b_gcn)[fl];
  float2 bs = ((const float2*)bl)[fl];
  float2 ba = ((const float2*)b_gat)[fl];
  float dd2 = dd * dd;
  float cinv = 1.0f / fmaxf((float)c, 1.0f);
  float gdi = 1.0f / (dg + exl + 1e-16f);
  float g0 = ag0 + dd2 * bflo(hg) + bg.x;
  float g1 = ag1 + dd2 * bfhi(hg) + bg.y;
  float s0 = as0 * cinv + bs.x + bflo(hr);
  float s1 = as1 * cinv + bs.y + bfhi(hr);
  float t0 = (aa0 + exl * bflo(ht)) * gdi + ba.x;
  float t1 = (aa1 + exl * bfhi(ht)) * gdi + ba.y;
  float w0 = w[0], w1 = w[1], w2 = w[2];
  float e0 = w0 * gelu_exact(g0) + w1 * gelu_exact(s0) + w2 * gelu_exact(t0);
  float e1 = w0 * gelu_exact(g1) + w1 * gelu_exact(s1) + w2 * gelu_exact(t1);
  if (half == 0) ((uint_t*)ensb)[(size_t)node * 32 + fl] = f2bf2(e0, e1);
}

// ---------------- MFMA GEMM B: QKVSb = bf16(ens @ [Wq|Wk|Wv|Wskip] + bias) -----
__global__ __launch_bounds__(256) void k_gemmB(
    const ushort_t* __restrict__ ensb, const ushort_t* __restrict__ WtB,
    const float* __restrict__ bcat, ushort_t* __restrict__ QKVSb) {
  __shared__ __align__(16) ushort_t wb[160 * 72];  // [c][k] padded +8
  __shared__ float bsh[160];
  const int t = threadIdx.x;
  for (int idx = t; idx < 160 * 8; idx += 256) {
    int c = idx >> 3, ch = idx & 7;
    *(uint4*)&wb[c * 72 + ch * 8] = *(const uint4*)(WtB + c * 64 + ch * 8);
  }
  if (t < 160) bsh[t] = bcat[t];
  __syncthreads();
  const int wv = t >> 6, l = t & 63;
  const int lr = l & 15, lg = l >> 4;
  const int rbase = blockIdx.x * 64 + wv * 16;
  int arow = rbase + lr;
  int arowc = arow < NN ? arow : NN - 1;
  const ushort_t* ap = ensb + (size_t)arowc * 64 + lg * 8;
  f32x4 acc[10] = {};
#pragma unroll
  for (int ks = 0; ks < 2; ++ks) {
    s16x8 af = *(const s16x8*)(ap + ks * 32);
#pragma unroll
    for (int n = 0; n < 10; ++n) {
      s16x8 bf = *(const s16x8*)&wb[(n * 16 + lr) * 72 + ks * 32 + lg * 8];
      acc[n] = __builtin_amdgcn_mfma_f32_16x16x32_bf16(af, bf, acc[n], 0, 0, 0);
    }
  }
#pragma unroll
  for (int n = 0; n < 10; ++n) {
    int col = n * 16 + lr;
#pragma unroll
    for (int j = 0; j < 4; ++j) {
      int orow = rbase + lg * 4 + j;
      if (orow < NN)
        QKVSb[(size_t)orow * 160 + col] = f2bf(acc[n][j] + bsh[col]);
    }
  }
}

// ---------------- edge-parallel transformer scores (8 lanes/edge) --------------
__global__ __launch_bounds__(256) void k_score(
    const int* __restrict__ srcidx, const int* __restrict__ dsts,
    const ushort_t* __restrict__ QKVSb, float* __restrict__ escore) {
  int p = (blockIdx.x * 256 + threadIdx.x) >> 3;
  int l = threadIdx.x & 7;
  if (p >= EE) return;
  int s = srcidx[p], d = dsts[p];
  float part = 0.f;
  if (l < 5) {
    const uint4 qv = *(const uint4*)(QKVSb + (size_t)d * 160 + l * 8);
    const uint4 kv = *(const uint4*)(QKVSb + (size_t)s * 160 + 40 + l * 8);
    part = bflo(qv.x) * bflo(kv.x);
    part = fmaf(bfhi(qv.x), bfhi(kv.x), part);
    part = fmaf(bflo(qv.y), bflo(kv.y), part);
    part = fmaf(bfhi(qv.y), bfhi(kv.y), part);
    part = fmaf(bflo(qv.z), bflo(kv.z), part);
    part = fmaf(bfhi(qv.z), bfhi(kv.z), part);
    part = fmaf(bflo(qv.w), bflo(kv.w), part);
    part = fmaf(bfhi(qv.w), bfhi(kv.w), part);
  }
  part += __shfl_xor(part, 1, 64);
  part += __shfl_xor(part, 2, 64);
  part += __shfl_xor(part, 4, 64);
  if (l == 0) escore[p] = __expf(part * 0.15811388300841897f);
}

// ---------------- transformer aggregation + log_softmax ------------------------
__global__ __launch_bounds__(256) void k_agg2(
    const int* __restrict__ srcidx, const int* __restrict__ offs,
    const int* __restrict__ cnt, const ushort_t* __restrict__ QKVSb,
    const float* __restrict__ escore, float* __restrict__ out) {
  int node = (blockIdx.x * blockDim.x + threadIdx.x) >> 6;
  int lane = threadIdx.x & 63;
  if (node >= NN) return;
  const int half = lane >> 5;
  const int fl = lane & 31;   // feature-pair index (feats 2fl, 2fl+1 of 40)
  const bool valid = fl < 20;
  int beg = offs[node];
  int end = beg + cnt[node];
  float den = 0.f, av0 = 0.f, av1 = 0.f;
  int p = beg + half;
  for (; p + 6 < end; p += 8) {
    int sA = srcidx[p], sB = srcidx[p + 2], sC = srcidx[p + 4],
        sD = srcidx[p + 6];
    float eA = escore[p], eB = escore[p + 2], eC = escore[p + 4],
          eD = escore[p + 6];
    uint_t vA = valid ? ((const uint_t*)(QKVSb + (size_t)sA * 160))[40 + fl] : 0u;
    uint_t vB = valid ? ((const uint_t*)(QKVSb + (size_t)sB * 160))[40 + fl] : 0u;
    uint_t vC = valid ? ((const uint_t*)(QKVSb + (size_t)sC * 160))[40 + fl] : 0u;
    uint_t vD = valid ? ((const uint_t*)(QKVSb + (size_t)sD * 160))[40 + fl] : 0u;
    av0 = fmaf(eA, bflo(vA), av0); av1 = fmaf(eA, bfhi(vA), av1);
    av0 = fmaf(eB, bflo(vB), av0); av1 = fmaf(eB, bfhi(vB), av1);
    av0 = fmaf(eC, bflo(vC), av0); av1 = fmaf(eC, bfhi(vC), av1);
    av0 = fmaf(eD, bflo(vD), av0); av1 = fmaf(eD, bfhi(vD), av1);
    den += (eA + eB) + (eC + eD);
  }
  for (; p < end; p += 2) {
    int sA = srcidx[p];
    float eA = escore[p];
    uint_t vA = valid ? ((const uint_t*)(QKVSb + (size_t)sA * 160))[40 + fl] : 0u;
    av0 = fmaf(eA, bflo(vA), av0); av1 = fmaf(eA, bfhi(vA), av1);
    den += eA;
  }
  // fold halves
  av0 += __shfl_xor(av0, 32, 64);
  av1 += __shfl_xor(av1, 32, 64);
  den += __shfl_xor(den, 32, 64);
  const uint_t* rd = (const uint_t*)(QKVSb + (size_t)node * 160);
  uint_t sk = valid ? rd[60 + fl] : 0u;
  float di = 1.0f / (den + 1e-16f);
  float o0 = valid ? av0 * di + bflo(sk) : -3.0e38f;
  float o1 = valid ? av1 * di + bfhi(sk) : -3.0e38f;
  float m = half_max(fmaxf(o0, o1));
  float eo = valid ? __expf(o0 - m) + __expf(o1 - m) : 0.f;
  float ls = logf(half_sum(eo));
  if (valid && half == 0) {
    float2 r = make_float2(o0 - m - ls, o1 - m - ls);
    ((float2*)out)[(size_t)node * 20 + fl] = r;
  }
}

extern "C" void kernel_launch(void* const* d_in, const int* in_sizes, int n_in,
                              void* d_out, int out_size, void* d_ws,
                              size_t ws_size, hipStream_t stream) {
  const float* x     = (const float*)d_in[0];
  const int*   ei    = (const int*)d_in[1];
  const float* w     = (const float*)d_in[2];
  const float* W_gcn = (const float*)d_in[3];
  const float* b_gcn = (const float*)d_in[4];
  const float* Wl    = (const float*)d_in[5];
  const float* bl    = (const float*)d_in[6];
  const float* Wr    = (const float*)d_in[7];
  const float* W_gat = (const float*)d_in[8];
  const float* att_s = (const float*)d_in[9];
  const float* att_d = (const float*)d_in[10];
  const float* b_gat = (const float*)d_in[11];
  const float* Wq    = (const float*)d_in[12];
  const float* bq    = (const float*)d_in[13];
  const float* Wk    = (const float*)d_in[14];
  const float* bk    = (const float*)d_in[15];
  const float* Wv    = (const float*)d_in[16];
  const float* bv    = (const float*)d_in[17];
  const float* Wsk   = (const float*)d_in[18];
  const float* bsk   = (const float*)d_in[19];
  float* out = (float*)d_out;
  float* ws  = (float*)d_ws;

  const int* src = ei;
  const int* dst = ei + EE;

  // workspace layout (float-unit offsets)
  ushort_t* Hb     = (ushort_t*)ws;                       // 128N fl
  ushort_t* ensb   = (ushort_t*)(ws + (size_t)128 * NN);  // 32N fl
  float*    a_s    = ws + (size_t)160 * NN;               // N
  float*    a_d    = ws + (size_t)161 * NN;               // N
  float*    dinv   = ws + (size_t)162 * NN;               // N
  ushort_t* qkvsb  = (ushort_t*)(ws + (size_t)163 * NN);  // 80N fl
  ushort_t* xb     = (ushort_t*)(ws + (size_t)243 * NN);  // 64N fl
  ushort_t* WtA    = (ushort_t*)(ws + (size_t)307 * NN);  // 16384 fl
  ushort_t* WtB    = (ushort_t*)(ws + (size_t)307 * NN + 16384);  // 5120 fl
  float*    bcat   = ws + (size_t)307 * NN + 21504;       // 160 fl
  float*    escore = ws + (size_t)307 * NN + 21664;       // EE fl
  float2*   edata  = (float2*)(ws + (size_t)307 * NN + 21664 + EE);  // 2EE fl
  int*      ibase  = (int*)(ws + (size_t)307 * NN + 21664 + 3 * (size_t)EE);
  int*      cnt    = ibase;                               // N
  int*      offs   = ibase + NN;                          // N
  int*      srcidx = ibase + 2 * NN;                      // EE
  int*      dsts   = ibase + 2 * NN + EE;                 // EE
  int*      erank  = ibase + 2 * NN + 2 * EE;             // EE
  int*      bsum   = ibase + 2 * NN + 3 * EE;             // NBLK

  hipMemsetAsync(cnt, 0, (size_t)NN * sizeof(int), stream);

  k_prep<<<PREP_CAST + PREP_W + PREP_HIST, 256, 0, stream>>>(
      x, dst, W_gcn, Wl, W_gat, Wr, Wq, Wk, Wv, Wsk, bq, bk, bv, bsk, xb, WtA,
      WtB, bcat, cnt, erank);

  dim3 gA((NN + 63) / 64, 4);
  k_gemmA<<<gA, 256, 0, stream>>>(xb, WtA, att_s, att_d, Hb, a_s, a_d);
  k_bsum<<<NBLK, SCB, 0, stream>>>(cnt, bsum);
  k_scanapply<<<NBLK, SCB, 0, stream>>>(cnt, bsum, offs, dinv);
  k_scatter<<<(EE + 255) / 256, 256, 0, stream>>>(src, dst, erank, offs, a_s,
                                                  a_d, dinv, srcidx, dsts,
                                                  edata);
  k_agg1<<<(NN + 3) / 4, 256, 0, stream>>>(srcidx, offs, cnt, Hb, edata, dinv,
                                           a_s, a_d, b_gcn, bl, b_gat, w, ensb);
  k_gemmB<<<(NN + 63) / 64, 256, 0, stream>>>(ensb, WtB, bcat, qkvsb);
  k_score<<<(EE * 8 + 255) / 256, 256, 0, stream>>>(srcidx, dsts, qkvsb,
                                                    escore);
  k_agg2<<<(NN + 3) / 4, 256, 0, stream>>>(srcidx, offs, cnt, qkvsb, escore,
                                           out);
}